// Round 6
// baseline (2985.584 us; speedup 1.0000x reference)
//
#include <hip/hip_runtime.h>
#include <math.h>

// ---------------- static config ----------------
#define NF 32
#define NPATHS 34
#define W3JTOT 3436

typedef __attribute__((ext_vector_type(8))) short bf16x8;
typedef __attribute__((ext_vector_type(4))) float f32x4;

__device__ __forceinline__ unsigned short f2bf(float v){
  unsigned u = __float_as_uint(v);
  u += 0x7fffu + ((u>>16)&1u);
  return (unsigned short)(u>>16);
}
__device__ __forceinline__ float bf2f(unsigned short h){
  return __uint_as_float(((unsigned)h)<<16);
}

struct PathTab { int l1[NPATHS]; int l2[NPATHS]; int l3[NPATHS]; int off[NPATHS]; int total; };
constexpr PathTab mkpaths(){
  PathTab t{}; int n=0; int off=0;
  for(int a=0;a<=3;a++)for(int b=0;b<=3;b++)for(int c=0;c<=3;c++){
    int lo = a>b ? a-b : b-a;
    if(c>=lo && c<=a+b){ t.l1[n]=a; t.l2[n]=b; t.l3[n]=c; t.off[n]=off;
      off += (2*a+1)*(2*b+1)*(2*c+1); n++; }
  }
  t.total=off; return t;
}
constexpr PathTab PT = mkpaths();
static_assert(PT.total==W3JTOT, "w3j table size");

__host__ __device__ constexpr int pathoff(int a0,int b0,int c0){
  int off=0;
  for(int a=0;a<=3;a++)for(int b=0;b<=3;b++)for(int c=0;c<=3;c++){
    int lo = a>b ? a-b : b-a;
    if(c<lo||c>a+b) continue;
    if(a==a0&&b==b0&&c==c0) return off;
    off += (2*a+1)*(2*b+1)*(2*c+1);
  }
  return -1;
}

// superset filter of real-w3j nonzeros: |mc| must equal |ma+mb| or |ma-mb|
__host__ __device__ constexpr bool msel(int ma,int mb,int mc){
  int s=ma+mb, d=ma-mb;
  int as = s<0?-s:s, ad = d<0?-d:d, ac = mc<0?-mc:mc;
  return (ac==as) || (ac==ad);
}

// ---------------- device W3J construction (exact replica of reference) ----------------
struct cdbl { double x, y; };
__device__ inline cdbl cmul(cdbl a, cdbl b){ return {a.x*b.x-a.y*b.y, a.x*b.y+a.y*b.x}; }
__device__ inline double dfact(int n){ double r=1.0; for(int i=2;i<=n;i++) r*=(double)i; return r; }

__device__ cdbl qval(int l,int r,int col){
  const double is2 = 0.70710678118654752440;
  double re=0.0, im=0.0;
  if (r<l){ if (col==2*l-r) re=is2; else if (col==r) im=-is2; }
  else if (r==l){ if (col==l) re=1.0; }
  else { double s = ((r-l)&1)? -1.0:1.0;
         if (col==r) re=s*is2; else if (col==2*l-r) im=s*is2; }
  cdbl v{re,im};
  switch(l&3){           // multiply by (-i)^l
    case 1: return { v.y, -v.x };
    case 2: return {-v.x, -v.y };
    case 3: return {-v.y,  v.x };
    default: return v;
  }
}

__device__ double cgval(int j1,int j2,int j3,int a,int b,int c){
  int m1=a-j1, m2=b-j2, m3=c-j3;
  if (m1+m2!=m3) return 0.0;
  double pref = (double)(2*j3+1)*dfact(j3+j1-j2)*dfact(j3-j1+j2)*dfact(j1+j2-j3)/dfact(j1+j2+j3+1);
  pref *= dfact(j3+m3)*dfact(j3-m3)*dfact(j1-m1)*dfact(j1+m1)*dfact(j2-m2)*dfact(j2+m2);
  pref = sqrt(pref);
  int k0 = 0; if (j2-j3-m1>k0) k0=j2-j3-m1; if (j1-j3+m2>k0) k0=j1-j3+m2;
  int k1 = j1+j2-j3; if (j1-m1<k1) k1=j1-m1; if (j2+m2<k1) k1=j2+m2;
  double s=0.0;
  for(int k=k0;k<=k1;k++){
    double d = dfact(k)*dfact(j1+j2-j3-k)*dfact(j1-m1-k)*dfact(j2+m2-k)*dfact(j3-j2+m1+k)*dfact(j3-j1-m2+k);
    s += ((k&1)? -1.0:1.0)/d;
  }
  return pref*s;
}

__global__ void k_init_w3j(float* __restrict__ w3jd, float* __restrict__ w3jn){
  int t = blockIdx.x*256 + threadIdx.x;
  if (t >= W3JTOT) return;
  int l1=0,l2=0,l3=0,loc=0;
  {
    int off=0; bool found=false;
    for(int a=0;a<=3&&!found;a++)for(int b=0;b<=3&&!found;b++)for(int c=0;c<=3&&!found;c++){
      int lo=a>b?a-b:b-a;
      if(c<lo||c>a+b) continue;
      int sz=(2*a+1)*(2*b+1)*(2*c+1);
      if (t < off+sz){ l1=a;l2=b;l3=c;loc=t-off;found=true; }
      off+=sz;
    }
  }
  int d2=2*l2+1, d3=2*l3+1;
  int i = loc/(d2*d3), j=(loc/d3)%d2, k=loc%d3;
  cdbl acc{0.0,0.0};
  for(int a=0;a<2*l1+1;a++){
    cdbl qa=qval(l1,a,i); if (qa.x==0.0&&qa.y==0.0) continue;
    for(int b=0;b<d2;b++){
      cdbl qb=qval(l2,b,j); if (qb.x==0.0&&qb.y==0.0) continue;
      cdbl qab=cmul(qa,qb);
      for(int c=0;c<d3;c++){
        double cg=cgval(l1,l2,l3,a,b,c); if (cg==0.0) continue;
        cdbl qc=qval(l3,c,k); qc.y=-qc.y;
        if (qc.x==0.0&&qc.y==0.0) continue;
        cdbl term=cmul(qab,qc);
        acc.x += cg*term.x; acc.y += cg*term.y;
      }
    }
  }
  w3jd[t]=(float)acc.x;
  w3jn[t]=(float)(acc.x/sqrt((double)(2*l3+1)));
}

__global__ void k_init_scales(const float* __restrict__ w3jd, float* __restrict__ scl){
  if (threadIdx.x!=0||blockIdx.x!=0) return;
  double v0=0.2,v1=-0.6,v2=0.7;
  double nv=sqrt(v0*v0+v1*v1+v2*v2);
  double s3=sqrt(3.0);
  double y1[3]={s3*v0/nv, s3*v1/nv, s3*v2/nv};
  const int o112 = pathoff(1,1,2);
  const int o213 = pathoff(2,1,3);
  double t2[5]; double n2=0.0;
  for(int c=0;c<5;c++){ double s=0.0;
    for(int a=0;a<3;a++)for(int b=0;b<3;b++) s += (double)w3jd[o112+(a*3+b)*5+c]*y1[a]*y1[b];
    t2[c]=s; n2+=s*s; }
  double sc2 = sqrt(5.0)/sqrt(n2);
  double y2[5]; for(int c=0;c<5;c++) y2[c]=sc2*t2[c];
  double n3=0.0;
  for(int c=0;c<7;c++){ double s=0.0;
    for(int a=0;a<5;a++)for(int b=0;b<3;b++) s += (double)w3jd[o213+(a*3+b)*7+c]*y2[a]*y1[b];
    n3+=s*s; }
  double sc3=sqrt(7.0)/sqrt(n3);
  scl[0]=(float)sc2; scl[1]=(float)sc3;
}

// ---------------- CSR build: degree count, scan, fill ----------------
__global__ __launch_bounds__(256) void k_count(
    const int* __restrict__ rcv, int* __restrict__ deg, int E)
{
  int e=blockIdx.x*256+threadIdx.x;
  if(e>=E) return;
  atomicAdd(&deg[rcv[e]],1);
}

#define SCAN_PER 32
__global__ __launch_bounds__(1024) void k_scan(
    const int* __restrict__ deg, int* __restrict__ row,
    int* __restrict__ cur, int N)
{
  __shared__ int part[1024];
  int t=threadIdx.x;
  int per=(N+1023)/1024; if(per>SCAN_PER) per=SCAN_PER;
  int base=t*per;
  int loc[SCAN_PER];
  int s=0;
  for(int i=0;i<per;i++){ int idx=base+i; int v=(idx<N)? deg[idx]:0; loc[i]=s; s+=v; }
  part[t]=s;
  __syncthreads();
  for(int off=1;off<1024;off<<=1){
    int v=(t>=off)? part[t-off]:0;
    __syncthreads();
    part[t]+=v;
    __syncthreads();
  }
  int ex=(t==0)?0:part[t-1];
  for(int i=0;i<per;i++){
    int idx=base+i;
    if(idx<N){ int r=ex+loc[i]; row[idx]=r; cur[idx]=r; }
  }
  if(t==1023) row[N]=part[1023];
}

__global__ __launch_bounds__(256) void k_fill(
    const int* __restrict__ rcv, int* __restrict__ cur,
    int* __restrict__ eid, int E)
{
  int e=blockIdx.x*256+threadIdx.x;
  if(e>=E) return;
  int pos=atomicAdd(&cur[rcv[e]],1);
  eid[pos]=e;
}

// ---------------- per-edge geometry (receiver-sorted order): SH + radial basis ----------------
__global__ __launch_bounds__(256) void k_edge_setup(
    const float* __restrict__ vec, const int* __restrict__ snd,
    const int* __restrict__ eid, float* __restrict__ Y,
    float* __restrict__ rad, int* __restrict__ snd_s,
    const float* __restrict__ w3, const float* __restrict__ scl, int E)
{
  int j = blockIdx.x*256+threadIdx.x;
  if (j>=E) return;
  int e = eid[j];
  snd_s[j]=snd[e];
  float vx=vec[3*e], vy=vec[3*e+1], vz=vec[3*e+2];
  float r=sqrtf(vx*vx+vy*vy+vz*vz);
  float inv=1.0f/fmaxf(r,1e-9f);
  float y[16];
  y[0]=1.0f;
  const float s3=1.7320508075688772f;
  y[1]=s3*vx*inv; y[2]=s3*vy*inv; y[3]=s3*vz*inv;
  float sc2=scl[0], sc3=scl[1];
  {
    constexpr int O = pathoff(1,1,2);
    #pragma unroll
    for(int c=0;c<5;c++){
      float s=0.f;
      #pragma unroll
      for(int a=0;a<3;a++){
        #pragma unroll
        for(int b=0;b<3;b++){
          if (!msel(a-1,b-1,c-2)) continue;
          s = fmaf(w3[O+(a*3+b)*5+c], y[1+a]*y[1+b], s);
        }
      }
      y[4+c]=sc2*s;
    }
  }
  {
    constexpr int O = pathoff(2,1,3);
    #pragma unroll
    for(int c=0;c<7;c++){
      float s=0.f;
      #pragma unroll
      for(int a=0;a<5;a++){
        #pragma unroll
        for(int b=0;b<3;b++){
          if (!msel(a-2,b-1,c-3)) continue;
          s = fmaf(w3[O+(a*3+b)*7+c], y[4+a]*y[1+b], s);
        }
      }
      y[9+c]=sc3*s;
    }
  }
  float4* Yp=(float4*)(Y+(size_t)j*16);
  Yp[0]=make_float4(y[0],y[1],y[2],y[3]);
  Yp[1]=make_float4(y[4],y[5],y[6],y[7]);
  Yp[2]=make_float4(y[8],y[9],y[10],y[11]);
  Yp[3]=make_float4(y[12],y[13],y[14],y[15]);
  float x = r*0.2f;
  float env=0.f;
  if (x<1.0f){
    float x2=x*x; float x4=x2*x2; float x5=x4*x;
    env = 1.0f - 21.0f*x5 + 35.0f*x5*x - 15.0f*x5*x2;
  }
  const float cb = 0.632455532033675866f; // sqrt(2/5)
  float base = inv*env*cb;
  #pragma unroll
  for(int n=1;n<=8;n++)
    rad[(size_t)j*8 + n-1] = base*sinf(3.14159265358979323846f * x * (float)n);
}

// ---------------- node init: scalar embedding ----------------
__global__ __launch_bounds__(256) void k_node_init(
    const float* __restrict__ embed, const int* __restrict__ z,
    float* __restrict__ feats, int N)
{
  int t = blockIdx.x*256+threadIdx.x;
  int n=t>>5, f=t&31;
  if(n>=N) return;
  float v = embed[z[n]*NF + f];
  float4* p=(float4*)(feats + (size_t)n*512 + f*16);
  p[0]=make_float4(v,0.f,0.f,0.f);
  p[1]=make_float4(0.f,0.f,0.f,0.f);
  p[2]=make_float4(0.f,0.f,0.f,0.f);
  p[3]=make_float4(0.f,0.f,0.f,0.f);
}

// ---------------- per-l channel-mixing linear (optionally per-species weights) ----------------
__global__ __launch_bounds__(256) void k_lin(
    const float* __restrict__ in, float* __restrict__ out,
    const float* __restrict__ w, const int* __restrict__ z, int zstride, int N)
{
  int t=blockIdx.x*256+threadIdx.x;
  int n=t>>5, g=t&31;
  if(n>=N) return;
  const float* wp = w + (z ? (size_t)z[n]*(size_t)zstride : 0);
  const float* ip = in + (size_t)n*512;
  float acc[16];
  #pragma unroll
  for(int c=0;c<16;c++) acc[c]=0.f;
  #pragma unroll 8
  for(int f=0; f<NF; f++){
    const float4* xp = (const float4*)(ip + f*16);
    float4 x0=xp[0], x1=xp[1], x2=xp[2], x3=xp[3];
    float w0v=wp[(f<<5)+g], w1v=wp[1024+(f<<5)+g], w2v=wp[2048+(f<<5)+g], w3v=wp[3072+(f<<5)+g];
    acc[0]  = fmaf(x0.x,w0v,acc[0]);
    acc[1]  = fmaf(x0.y,w1v,acc[1]);
    acc[2]  = fmaf(x0.z,w1v,acc[2]);
    acc[3]  = fmaf(x0.w,w1v,acc[3]);
    acc[4]  = fmaf(x1.x,w2v,acc[4]);
    acc[5]  = fmaf(x1.y,w2v,acc[5]);
    acc[6]  = fmaf(x1.z,w2v,acc[6]);
    acc[7]  = fmaf(x1.w,w2v,acc[7]);
    acc[8]  = fmaf(x2.x,w2v,acc[8]);
    acc[9]  = fmaf(x2.y,w3v,acc[9]);
    acc[10] = fmaf(x2.z,w3v,acc[10]);
    acc[11] = fmaf(x2.w,w3v,acc[11]);
    acc[12] = fmaf(x3.x,w3v,acc[12]);
    acc[13] = fmaf(x3.y,w3v,acc[13]);
    acc[14] = fmaf(x3.z,w3v,acc[14]);
    acc[15] = fmaf(x3.w,w3v,acc[15]);
  }
  float4* op=(float4*)(out + (size_t)n*512 + g*16);
  op[0]=make_float4(acc[0],acc[1],acc[2],acc[3]);
  op[1]=make_float4(acc[4],acc[5],acc[6],acc[7]);
  op[2]=make_float4(acc[8],acc[9],acc[10],acc[11]);
  op[3]=make_float4(acc[12],acc[13],acc[14],acc[15]);
}

// ---------------- radial MLP hidden layers (bf16 output) ----------------
__global__ __launch_bounds__(256) void k_radial(
    const float* __restrict__ rad, const float* __restrict__ w0,
    const float* __restrict__ w1, unsigned short* __restrict__ hid, int E)
{
  __shared__ float w0s[8*64];
  __shared__ float w1s[64*64];
  int tid=threadIdx.x;
  for(int i=tid;i<512;i+=256) w0s[i]=w0[i];
  for(int i=tid;i<4096;i+=256) w1s[i]=w1[i];
  __syncthreads();
  int e=blockIdx.x*256+tid;
  if(e>=E) return;
  const float4* rp=(const float4*)(rad+(size_t)e*8);
  float4 ra=rp[0], rb=rp[1];
  float rv[8]={ra.x,ra.y,ra.z,ra.w,rb.x,rb.y,rb.z,rb.w};
  float h1[64];
  #pragma unroll 8
  for(int j=0;j<64;j++){
    float a=0.f;
    #pragma unroll
    for(int i=0;i<8;i++) a=fmaf(rv[i],w0s[i*64+j],a);
    h1[j]=a/(1.f+__expf(-a));
  }
  unsigned short* hp = hid+(size_t)e*64;
  #pragma unroll 4
  for(int j=0;j<64;j++){
    float a=0.f;
    #pragma unroll
    for(int i=0;i<64;i++) a=fmaf(h1[i],w1s[i*64+j],a);
    hp[j]=f2bf(a/(1.f+__expf(-a)));
  }
}

// ---------------- cast+transpose w2 [64 x 1088] -> w2t [1088 x 64] bf16 ----------------
__global__ __launch_bounds__(256) void k_cast_w2t(
    const float* __restrict__ w2, unsigned short* __restrict__ w2t)
{
  int t=blockIdx.x*256+threadIdx.x;
  if(t>=1088*64) return;
  int c=t>>6, k=t&63;
  w2t[(size_t)c*64+k]=f2bf(w2[(size_t)k*1088+c]);
}

// ---------------- rw GEMM via MFMA, f-major padded epilogue ----------------
// C layout: [row][f][p] with p padded to PADP; logical col c -> (p=c>>5, f=c&31).
// Layouts (HW-verified m89/m120): A-frag A[m=lane&15][k=quad*8+j];
// B-frag B[k=quad*8+j][n=lane&15]; D: row=quad*4+reg, col=lane&15.
template<int PADP>
__global__ __launch_bounds__(256) void k_gemm_mfma(
    const unsigned short* __restrict__ A, const unsigned short* __restrict__ Bt,
    unsigned short* __restrict__ C, int ncols)
{
  const int ldc = 32*PADP;
  int wave = threadIdx.x>>6;
  int lane = threadIdx.x&63;
  int m16 = lane&15, quad = lane>>4;
  size_t rowbase = (size_t)blockIdx.y*64;
  int col0 = blockIdx.x*128 + wave*32;
  f32x4 acc[4][2];
  #pragma unroll
  for(int mt=0;mt<4;mt++){
    #pragma unroll
    for(int nt=0;nt<2;nt++) acc[mt][nt]=(f32x4){0.f,0.f,0.f,0.f};
  }
  #pragma unroll
  for(int ks=0;ks<2;ks++){
    bf16x8 a[4], b[2];
    #pragma unroll
    for(int mt=0;mt<4;mt++)
      a[mt] = *(const bf16x8*)(A + (rowbase+mt*16+m16)*64 + ks*32 + quad*8);
    #pragma unroll
    for(int nt=0;nt<2;nt++){
      int c = col0 + nt*16 + m16;
      if (c<ncols) b[nt] = *(const bf16x8*)(Bt + (size_t)c*64 + ks*32 + quad*8);
      else         b[nt] = (bf16x8){0,0,0,0,0,0,0,0};
    }
    #pragma unroll
    for(int mt=0;mt<4;mt++){
      #pragma unroll
      for(int nt=0;nt<2;nt++)
        acc[mt][nt]=__builtin_amdgcn_mfma_f32_16x16x32_bf16(a[mt],b[nt],acc[mt][nt],0,0,0);
    }
  }
  #pragma unroll
  for(int mt=0;mt<4;mt++){
    #pragma unroll
    for(int nt=0;nt<2;nt++){
      int c = col0 + nt*16 + m16;
      if (c>=ncols) continue;
      int dst = (c&31)*PADP + (c>>5);
      #pragma unroll
      for(int r=0;r<4;r++){
        size_t row = rowbase + mt*16 + quad*4 + r;
        C[row*(size_t)ldc + dst] = f2bf(acc[mt][nt][r]);
      }
    }
  }
}

// ---------------- edge tensor product -> per-edge messages (receiver-sorted) ----------------
// rw layout: [edge][f][p padded to PADP] bf16; msgs layout: [edge][f][16] bf16.
template<bool L0>
__global__ __launch_bounds__(256) void k_tp_msg(
    const float* __restrict__ hlin, const float* __restrict__ Y,
    const unsigned short* __restrict__ rw, const int* __restrict__ snd_s,
    const float* __restrict__ w3, unsigned short* __restrict__ msgs,
    int eb, int ecnt)
{
  constexpr int PADP = L0 ? 8 : 40;
  constexpr int RWLD = 32*PADP;
  int t=blockIdx.x*256+threadIdx.x;
  int el=t>>5, f=t&31;
  if(el>=ecnt) return;
  int j=eb+el;
  int s=snd_s[j];
  float hs[16];
  {
    const float* hp = hlin+(size_t)s*512+f*16;
    if (L0){
      hs[0]=hp[0];
      #pragma unroll
      for(int c=1;c<16;c++) hs[c]=0.f;
    } else {
      const float4* hv=(const float4*)hp;
      float4 a=hv[0],b=hv[1],cc=hv[2],d=hv[3];
      hs[0]=a.x; hs[1]=a.y; hs[2]=a.z; hs[3]=a.w;
      hs[4]=b.x; hs[5]=b.y; hs[6]=b.z; hs[7]=b.w;
      hs[8]=cc.x; hs[9]=cc.y; hs[10]=cc.z; hs[11]=cc.w;
      hs[12]=d.x; hs[13]=d.y; hs[14]=d.z; hs[15]=d.w;
    }
  }
  float yv[16];
  {
    const float4* yp=(const float4*)(Y+(size_t)j*16);
    float4 a=yp[0],b=yp[1],cc=yp[2],d=yp[3];
    yv[0]=a.x; yv[1]=a.y; yv[2]=a.z; yv[3]=a.w;
    yv[4]=b.x; yv[5]=b.y; yv[6]=b.z; yv[7]=b.w;
    yv[8]=cc.x; yv[9]=cc.y; yv[10]=cc.z; yv[11]=cc.w;
    yv[12]=d.x; yv[13]=d.y; yv[14]=d.z; yv[15]=d.w;
  }
  // vectorized rw load: contiguous, 16B-aligned
  bf16x8 rr[5];
  {
    const unsigned short* rp = rw + (size_t)el*RWLD + f*PADP;
    if (L0){
      rr[0]=*(const bf16x8*)rp;
    } else {
      #pragma unroll
      for(int i=0;i<5;i++) rr[i]=*(const bf16x8*)(rp+i*8);
    }
  }
  float acc[16];
  #pragma unroll
  for(int c=0;c<16;c++) acc[c]=0.f;
  #pragma unroll
  for(int p=0;p<NPATHS;p++){
    const int l1=PT.l1[p], l2=PT.l2[p], l3=PT.l3[p], off=PT.off[p];
    if (L0 && l1!=0) continue;
    const int pi = L0 ? ((p<4)?p:0) : p;   // L0 uses only paths 0..3
    const float rv = bf2f((unsigned short)rr[pi>>3][pi&7]);
    #pragma unroll
    for(int a=0;a<2*l1+1;a++){
      const float ha=hs[l1*l1+a];
      #pragma unroll
      for(int b=0;b<2*l2+1;b++){
        const float tt=ha*yv[l2*l2+b]*rv;
        #pragma unroll
        for(int c=0;c<2*l3+1;c++){
          if (!msel(a-l1,b-l2,c-l3)) continue;
          acc[l3*l3+c]=fmaf(w3[off+(a*(2*l2+1)+b)*(2*l3+1)+c],tt,acc[l3*l3+c]);
        }
      }
    }
  }
  bf16x8 m0, m1;
  #pragma unroll
  for(int c=0;c<8;c++){
    m0[c]=(short)f2bf(acc[c]*0.0625f);
    m1[c]=(short)f2bf(acc[8+c]*0.0625f);
  }
  bf16x8* mp=(bf16x8*)(msgs+(size_t)el*512+f*16);
  mp[0]=m0; mp[1]=m1;
}

// ---------------- CSR segment-sum of bf16 messages (no atomics) ----------------
__global__ __launch_bounds__(256) void k_seg_sum(
    const unsigned short* __restrict__ msgs, const int* __restrict__ row,
    float* __restrict__ agg, int eb, int ecnt, int N)
{
  int t=blockIdx.x*256+threadIdx.x;
  int n=t>>6, q=t&63;            // q indexes 8 consecutive floats; wave = 1 node
  if(n>=N) return;
  int lo=row[n], hi=row[n+1];
  int a0 = lo>eb ? lo : eb;
  int a1e = eb+ecnt;
  int a1 = hi<a1e ? hi : a1e;
  if(a0>=a1) return;
  float s[8];
  #pragma unroll
  for(int i=0;i<8;i++) s[i]=0.f;
  for(int j=a0;j<a1;j++){
    bf16x8 v=*(const bf16x8*)(msgs+(size_t)(j-eb)*512+q*8);
    #pragma unroll
    for(int i=0;i<8;i++) s[i]+=bf2f((unsigned short)v[i]);
  }
  float* ap=agg+(size_t)n*512+q*8;
  float4* a0p=(float4*)ap;
  float4 o0=a0p[0], o1=a0p[1];
  o0.x+=s[0]; o0.y+=s[1]; o0.z+=s[2]; o0.w+=s[3];
  o1.x+=s[4]; o1.y+=s[5]; o1.z+=s[6]; o1.w+=s[7];
  a0p[0]=o0; a0p[1]=o1;
}

// ---------------- node-wise symmetric tensor product (product basis) ----------------
__device__ __forceinline__ void tp_pair(const float* __restrict__ w3n,
    const float* __restrict__ x, const float* __restrict__ yy, float* __restrict__ o)
{
  #pragma unroll
  for(int p=0;p<NPATHS;p++){
    const int l1=PT.l1[p], l2=PT.l2[p], l3=PT.l3[p], off=PT.off[p];
    #pragma unroll
    for(int a=0;a<2*l1+1;a++){
      const float xa=x[l1*l1+a];
      #pragma unroll
      for(int b=0;b<2*l2+1;b++){
        const float tt=xa*yy[l2*l2+b];
        #pragma unroll
        for(int c=0;c<2*l3+1;c++){
          if(!msel(a-l1,b-l2,c-l3)) continue;
          o[l3*l3+c]=fmaf(w3n[off+(a*(2*l2+1)+b)*(2*l3+1)+c],tt,o[l3*l3+c]);
        }
      }
    }
  }
}

__global__ __launch_bounds__(256) void k_tp_node(
    const float* __restrict__ in, float* __restrict__ out,
    const float* __restrict__ w3n, const float* __restrict__ pb,
    const int* __restrict__ z, int N)
{
  int t=blockIdx.x*256+threadIdx.x;
  int n=t>>5, f=t&31;
  if(n>=N) return;
  float A[16];
  {
    const float4* p=(const float4*)(in+(size_t)n*512+f*16);
    float4 a=p[0],b=p[1],c=p[2],d=p[3];
    A[0]=a.x; A[1]=a.y; A[2]=a.z; A[3]=a.w;
    A[4]=b.x; A[5]=b.y; A[6]=b.z; A[7]=b.w;
    A[8]=c.x; A[9]=c.y; A[10]=c.z; A[11]=c.w;
    A[12]=d.x; A[13]=d.y; A[14]=d.z; A[15]=d.w;
  }
  float B2[16]; float B3[16];
  #pragma unroll
  for(int c=0;c<16;c++){ B2[c]=0.f; B3[c]=0.f; }
  tp_pair(w3n, A, A, B2);
  tp_pair(w3n, B2, A, B3);
  int zz=z[n];
  float wa=pb[zz*96+f], wb=pb[zz*96+32+f], wc=pb[zz*96+64+f];
  float o[16];
  #pragma unroll
  for(int c=0;c<16;c++) o[c]=wa*A[c]+wb*B2[c]+wc*B3[c];
  float4* op=(float4*)(out+(size_t)n*512+f*16);
  op[0]=make_float4(o[0],o[1],o[2],o[3]);
  op[1]=make_float4(o[4],o[5],o[6],o[7]);
  op[2]=make_float4(o[8],o[9],o[10],o[11]);
  op[3]=make_float4(o[12],o[13],o[14],o[15]);
}

// ---------------- readouts ----------------
__global__ __launch_bounds__(256) void k_resid(
    const float* __restrict__ feats, const float* __restrict__ res1,
    const int* __restrict__ z, float* __restrict__ resid, int N)
{
  int t=blockIdx.x*256+threadIdx.x;
  int n=t>>5, g=t&31;
  if(n>=N) return;
  const float* wp=res1+(size_t)z[n]*1024;
  float a=0.f;
  #pragma unroll 8
  for(int f=0;f<32;f++) a=fmaf(feats[(size_t)n*512+f*16], wp[(f<<5)+g], a);
  resid[(size_t)n*32+g]=a;
}

__global__ __launch_bounds__(256) void k_e0(
    const float* __restrict__ feats, const float* __restrict__ ro0,
    float* __restrict__ e0, int N)
{
  int n=blockIdx.x*256+threadIdx.x;
  if(n>=N) return;
  float a=0.f;
  #pragma unroll 8
  for(int f=0;f<32;f++) a=fmaf(feats[(size_t)n*512+f*16], ro0[f], a);
  e0[n]=a;
}

__global__ __launch_bounds__(256) void k_final(
    const float* __restrict__ h, const float* __restrict__ resid,
    const float* __restrict__ e0a, const float* __restrict__ ro1a,
    const float* __restrict__ ro1b, float* __restrict__ out, int N)
{
  int t=blockIdx.x*256+threadIdx.x;
  float val=0.f;
  if (t<N){
    float sc[32];
    #pragma unroll 8
    for(int f=0;f<32;f++) sc[f]=h[(size_t)t*512+f*16]+resid[(size_t)t*32+f];
    float e1=0.f;
    #pragma unroll
    for(int j=0;j<16;j++){
      float a=0.f;
      #pragma unroll
      for(int f=0;f<32;f++) a=fmaf(sc[f],ro1a[f*16+j],a);
      float s=a/(1.f+__expf(-a));
      e1=fmaf(s,ro1b[j],e1);
    }
    val = -1.5f + 2.0f*(e0a[t]+e1) - 10.0f;
  }
  __shared__ float red[256];
  red[threadIdx.x]=val;
  __syncthreads();
  for(int s=128;s>0;s>>=1){
    if(threadIdx.x<s) red[threadIdx.x]+=red[threadIdx.x+s];
    __syncthreads();
  }
  if(threadIdx.x==0) atomicAdd(out, red[0]);
}

// ---------------- host orchestration ----------------
extern "C" void kernel_launch(void* const* d_in, const int* in_sizes, int n_in,
                              void* d_out, int out_size, void* d_ws, size_t ws_size,
                              hipStream_t stream)
{
  const float* vec   =(const float*)d_in[0];
  const int*   zarr  =(const int*)  d_in[1];
  const int*   snd   =(const int*)  d_in[2];
  const int*   rcv   =(const int*)  d_in[3];
  const float* embed =(const float*)d_in[4];
  const float* r0w0  =(const float*)d_in[5];
  const float* r0w1  =(const float*)d_in[6];
  const float* r0w2  =(const float*)d_in[7];
  const float* up0   =(const float*)d_in[8];
  const float* post0 =(const float*)d_in[9];
  const float* pb0   =(const float*)d_in[10];
  const float* pblin0=(const float*)d_in[11];
  const float* r1w0  =(const float*)d_in[12];
  const float* r1w1  =(const float*)d_in[13];
  const float* r1w2  =(const float*)d_in[14];
  const float* up1   =(const float*)d_in[15];
  const float* post1 =(const float*)d_in[16];
  const float* pb1   =(const float*)d_in[17];
  const float* pblin1=(const float*)d_in[18];
  const float* sel0  =(const float*)d_in[19];
  const float* ro0   =(const float*)d_in[20];
  const float* res1  =(const float*)d_in[21];
  const float* ro1a  =(const float*)d_in[22];
  const float* ro1b  =(const float*)d_in[23];

  const int E = in_sizes[0]/3;
  const int N = in_sizes[1];
  const int Epad = (E+63)&~63;

  char* ws=(char*)d_ws;
  size_t o=0;
  auto alloc=[&](size_t bytes)->char*{
    char* p=ws+o;
    o=(o+bytes+255)&~(size_t)255;
    return p;
  };
  float* w3jd =(float*)alloc((size_t)W3JTOT*4);
  float* w3jn =(float*)alloc((size_t)W3JTOT*4);
  float* scl  =(float*)alloc(8);
  int*   deg  =(int*)  alloc((size_t)N*4);
  int*   rowp =(int*)  alloc((size_t)(N+1)*4);
  int*   cur  =(int*)  alloc((size_t)N*4);
  int*   eid  =(int*)  alloc((size_t)E*4);
  int*   snd_s=(int*)  alloc((size_t)E*4);
  float* Yb   =(float*)alloc((size_t)E*16*4);
  float* radb =(float*)alloc((size_t)E*8*4);
  unsigned short* hidb=(unsigned short*)alloc((size_t)Epad*64*2);
  unsigned short* w2t0=(unsigned short*)alloc((size_t)1088*64*2);
  unsigned short* w2t1=(unsigned short*)alloc((size_t)1088*64*2);
  float* feats=(float*)alloc((size_t)N*512*4);
  float* bufA =(float*)alloc((size_t)N*512*4);
  float* bufB =(float*)alloc((size_t)N*512*4);
  float* bufC =(float*)alloc((size_t)N*512*4);
  float* e0b  =(float*)alloc((size_t)N*4);
  float* residb=(float*)alloc((size_t)N*32*4);
  char*  dyn  = ws+o;
  size_t remain = ws_size>o ? ws_size-o : 0;

  dim3 tb(256);
  dim3 nblk((unsigned)((N*32+255)/256));
  dim3 eblk((unsigned)((E+255)/256));
  dim3 qblk((unsigned)((N*64+255)/256));

  k_init_w3j<<<dim3((W3JTOT+255)/256),tb,0,stream>>>(w3jd,w3jn);
  k_init_scales<<<dim3(1),dim3(64),0,stream>>>(w3jd,scl);

  // CSR build (receiver-sorted edge order)
  hipMemsetAsync(deg,0,(size_t)N*4,stream);
  k_count<<<eblk,tb,0,stream>>>(rcv,deg,E);
  k_scan<<<dim3(1),dim3(1024),0,stream>>>(deg,rowp,cur,N);
  k_fill<<<eblk,tb,0,stream>>>(rcv,cur,eid,E);

  k_edge_setup<<<eblk,tb,0,stream>>>(vec,snd,eid,Yb,radb,snd_s,w3jd,scl,E);
  k_node_init<<<nblk,tb,0,stream>>>(embed,zarr,feats,N);

  // cast+transpose radial-MLP final weights to bf16 (per launch)
  k_cast_w2t<<<dim3((1088*64+255)/256),tb,0,stream>>>(r0w2,w2t0);
  k_cast_w2t<<<dim3((1088*64+255)/256),tb,0,stream>>>(r1w2,w2t1);

  auto run_edges=[&](bool l0, const float* hlin, const unsigned short* w2t, float* agg){
    const int PADP = l0?8:40;
    const int rwld = 32*PADP;
    const int ncols = l0?128:1088;
    size_t per = (size_t)rwld*2 + 1024;      // rw(bf16, padded) + msgs(bf16) per edge
    long rows = (long)(remain/per);
    rows -= rows%64;
    if (rows>(long)Epad) rows=Epad;
    if (rows<64) rows=64;
    unsigned short* rwb = (unsigned short*)dyn;
    unsigned short* msgsb = (unsigned short*)(dyn + (((size_t)rows*(size_t)rwld*2 + 255)&~(size_t)255));
    for(long eb=0;eb<E;eb+=rows){
      long cnt = E-eb; if(cnt>rows) cnt=rows;
      long cntp = (cnt+63)&~63L;
      dim3 g((unsigned)((ncols+127)/128),(unsigned)(cntp/64));
      if(l0) k_gemm_mfma<8 ><<<g,tb,0,stream>>>(hidb+(size_t)eb*64, w2t, rwb, ncols);
      else   k_gemm_mfma<40><<<g,tb,0,stream>>>(hidb+(size_t)eb*64, w2t, rwb, ncols);
      dim3 g2((unsigned)((cnt*32+255)/256));
      if(l0) k_tp_msg<true ><<<g2,tb,0,stream>>>(hlin,Yb,rwb,snd_s,w3jd,msgsb,(int)eb,(int)cnt);
      else   k_tp_msg<false><<<g2,tb,0,stream>>>(hlin,Yb,rwb,snd_s,w3jd,msgsb,(int)eb,(int)cnt);
      k_seg_sum<<<qblk,tb,0,stream>>>(msgsb,rowp,agg,(int)eb,(int)cnt,N);
    }
  };

  // ---- layer 0 ----
  k_lin<<<nblk,tb,0,stream>>>(feats,bufA,up0,(const int*)nullptr,0,N);
  k_radial<<<eblk,tb,0,stream>>>(radb,r0w0,r0w1,hidb,E);
  hipMemsetAsync(bufB,0,(size_t)N*512*4,stream);
  run_edges(true,bufA,w2t0,bufB);
  k_lin<<<nblk,tb,0,stream>>>(bufB,bufC,post0,(const int*)nullptr,0,N);
  k_lin<<<nblk,tb,0,stream>>>(bufC,bufA,sel0,zarr,4096,N);
  k_tp_node<<<nblk,tb,0,stream>>>(bufA,bufB,w3jn,pb0,zarr,N);
  k_lin<<<nblk,tb,0,stream>>>(bufB,feats,pblin0,(const int*)nullptr,0,N);
  k_e0<<<dim3((N+255)/256),tb,0,stream>>>(feats,ro0,e0b,N);
  k_resid<<<nblk,tb,0,stream>>>(feats,res1,zarr,residb,N);

  // ---- layer 1 ----
  k_lin<<<nblk,tb,0,stream>>>(feats,bufA,up1,(const int*)nullptr,0,N);
  k_radial<<<eblk,tb,0,stream>>>(radb,r1w0,r1w1,hidb,E);
  hipMemsetAsync(bufC,0,(size_t)N*512*4,stream);
  run_edges(false,bufA,w2t1,bufC);
  k_lin<<<nblk,tb,0,stream>>>(bufC,bufB,post1,(const int*)nullptr,0,N);
  k_tp_node<<<nblk,tb,0,stream>>>(bufB,bufA,w3jn,pb1,zarr,N);
  k_lin<<<nblk,tb,0,stream>>>(bufA,bufC,pblin1,(const int*)nullptr,0,N);

  hipMemsetAsync(d_out,0,4,stream);
  k_final<<<dim3((N+255)/256),tb,0,stream>>>(bufC,residb,e0b,ro1a,ro1b,(float*)d_out,N);
}

// Round 7
// 2027.951 us; speedup vs baseline: 1.4722x; 1.4722x over previous
//
#include <hip/hip_runtime.h>
#include <math.h>

// ---------------- static config ----------------
#define NF 32
#define NPATHS 34
#define W3JTOT 3436

typedef __attribute__((ext_vector_type(8))) short bf16x8;
typedef __attribute__((ext_vector_type(4))) float f32x4;

__device__ __forceinline__ unsigned short f2bf(float v){
  unsigned u = __float_as_uint(v);
  u += 0x7fffu + ((u>>16)&1u);
  return (unsigned short)(u>>16);
}
__device__ __forceinline__ float bf2f(unsigned short h){
  return __uint_as_float(((unsigned)h)<<16);
}

struct PathTab { int l1[NPATHS]; int l2[NPATHS]; int l3[NPATHS]; int off[NPATHS]; int total; };
constexpr PathTab mkpaths(){
  PathTab t{}; int n=0; int off=0;
  for(int a=0;a<=3;a++)for(int b=0;b<=3;b++)for(int c=0;c<=3;c++){
    int lo = a>b ? a-b : b-a;
    if(c>=lo && c<=a+b){ t.l1[n]=a; t.l2[n]=b; t.l3[n]=c; t.off[n]=off;
      off += (2*a+1)*(2*b+1)*(2*c+1); n++; }
  }
  t.total=off; return t;
}
constexpr PathTab PT = mkpaths();
static_assert(PT.total==W3JTOT, "w3j table size");

__host__ __device__ constexpr int pathoff(int a0,int b0,int c0){
  int off=0;
  for(int a=0;a<=3;a++)for(int b=0;b<=3;b++)for(int c=0;c<=3;c++){
    int lo = a>b ? a-b : b-a;
    if(c<lo||c>a+b) continue;
    if(a==a0&&b==b0&&c==c0) return off;
    off += (2*a+1)*(2*b+1)*(2*c+1);
  }
  return -1;
}

// superset filter of real-w3j nonzeros: |mc| must equal |ma+mb| or |ma-mb|
__host__ __device__ constexpr bool msel(int ma,int mb,int mc){
  int s=ma+mb, d=ma-mb;
  int as = s<0?-s:s, ad = d<0?-d:d, ac = mc<0?-mc:mc;
  return (ac==as) || (ac==ad);
}

// ---------------- device W3J construction (exact replica of reference) ----------------
struct cdbl { double x, y; };
__device__ inline cdbl cmul(cdbl a, cdbl b){ return {a.x*b.x-a.y*b.y, a.x*b.y+a.y*b.x}; }
__device__ inline double dfact(int n){ double r=1.0; for(int i=2;i<=n;i++) r*=(double)i; return r; }

__device__ cdbl qval(int l,int r,int col){
  const double is2 = 0.70710678118654752440;
  double re=0.0, im=0.0;
  if (r<l){ if (col==2*l-r) re=is2; else if (col==r) im=-is2; }
  else if (r==l){ if (col==l) re=1.0; }
  else { double s = ((r-l)&1)? -1.0:1.0;
         if (col==r) re=s*is2; else if (col==2*l-r) im=s*is2; }
  cdbl v{re,im};
  switch(l&3){           // multiply by (-i)^l
    case 1: return { v.y, -v.x };
    case 2: return {-v.x, -v.y };
    case 3: return {-v.y,  v.x };
    default: return v;
  }
}

__device__ double cgval(int j1,int j2,int j3,int a,int b,int c){
  int m1=a-j1, m2=b-j2, m3=c-j3;
  if (m1+m2!=m3) return 0.0;
  double pref = (double)(2*j3+1)*dfact(j3+j1-j2)*dfact(j3-j1+j2)*dfact(j1+j2-j3)/dfact(j1+j2+j3+1);
  pref *= dfact(j3+m3)*dfact(j3-m3)*dfact(j1-m1)*dfact(j1+m1)*dfact(j2-m2)*dfact(j2+m2);
  pref = sqrt(pref);
  int k0 = 0; if (j2-j3-m1>k0) k0=j2-j3-m1; if (j1-j3+m2>k0) k0=j1-j3+m2;
  int k1 = j1+j2-j3; if (j1-m1<k1) k1=j1-m1; if (j2+m2<k1) k1=j2+m2;
  double s=0.0;
  for(int k=k0;k<=k1;k++){
    double d = dfact(k)*dfact(j1+j2-j3-k)*dfact(j1-m1-k)*dfact(j2+m2-k)*dfact(j3-j2+m1+k)*dfact(j3-j1-m2+k);
    s += ((k&1)? -1.0:1.0)/d;
  }
  return pref*s;
}

__global__ void k_init_w3j(float* __restrict__ w3jd, float* __restrict__ w3jn){
  int t = blockIdx.x*256 + threadIdx.x;
  if (t >= W3JTOT) return;
  int l1=0,l2=0,l3=0,loc=0;
  {
    int off=0; bool found=false;
    for(int a=0;a<=3&&!found;a++)for(int b=0;b<=3&&!found;b++)for(int c=0;c<=3&&!found;c++){
      int lo=a>b?a-b:b-a;
      if(c<lo||c>a+b) continue;
      int sz=(2*a+1)*(2*b+1)*(2*c+1);
      if (t < off+sz){ l1=a;l2=b;l3=c;loc=t-off;found=true; }
      off+=sz;
    }
  }
  int d2=2*l2+1, d3=2*l3+1;
  int i = loc/(d2*d3), j=(loc/d3)%d2, k=loc%d3;
  cdbl acc{0.0,0.0};
  for(int a=0;a<2*l1+1;a++){
    cdbl qa=qval(l1,a,i); if (qa.x==0.0&&qa.y==0.0) continue;
    for(int b=0;b<d2;b++){
      cdbl qb=qval(l2,b,j); if (qb.x==0.0&&qb.y==0.0) continue;
      cdbl qab=cmul(qa,qb);
      for(int c=0;c<d3;c++){
        double cg=cgval(l1,l2,l3,a,b,c); if (cg==0.0) continue;
        cdbl qc=qval(l3,c,k); qc.y=-qc.y;
        if (qc.x==0.0&&qc.y==0.0) continue;
        cdbl term=cmul(qab,qc);
        acc.x += cg*term.x; acc.y += cg*term.y;
      }
    }
  }
  w3jd[t]=(float)acc.x;
  w3jn[t]=(float)(acc.x/sqrt((double)(2*l3+1)));
}

__global__ void k_init_scales(const float* __restrict__ w3jd, float* __restrict__ scl){
  if (threadIdx.x!=0||blockIdx.x!=0) return;
  double v0=0.2,v1=-0.6,v2=0.7;
  double nv=sqrt(v0*v0+v1*v1+v2*v2);
  double s3=sqrt(3.0);
  double y1[3]={s3*v0/nv, s3*v1/nv, s3*v2/nv};
  const int o112 = pathoff(1,1,2);
  const int o213 = pathoff(2,1,3);
  double t2[5]; double n2=0.0;
  for(int c=0;c<5;c++){ double s=0.0;
    for(int a=0;a<3;a++)for(int b=0;b<3;b++) s += (double)w3jd[o112+(a*3+b)*5+c]*y1[a]*y1[b];
    t2[c]=s; n2+=s*s; }
  double sc2 = sqrt(5.0)/sqrt(n2);
  double y2[5]; for(int c=0;c<5;c++) y2[c]=sc2*t2[c];
  double n3=0.0;
  for(int c=0;c<7;c++){ double s=0.0;
    for(int a=0;a<5;a++)for(int b=0;b<3;b++) s += (double)w3jd[o213+(a*3+b)*7+c]*y2[a]*y1[b];
    n3+=s*s; }
  double sc3=sqrt(7.0)/sqrt(n3);
  scl[0]=(float)sc2; scl[1]=(float)sc3;
}

// ---------------- CSR build: degree count, scan, fill ----------------
__global__ __launch_bounds__(256) void k_count(
    const int* __restrict__ rcv, int* __restrict__ deg, int E)
{
  int e=blockIdx.x*256+threadIdx.x;
  if(e>=E) return;
  atomicAdd(&deg[rcv[e]],1);
}

#define SCAN_PER 32
__global__ __launch_bounds__(1024) void k_scan(
    const int* __restrict__ deg, int* __restrict__ row,
    int* __restrict__ cur, int N)
{
  __shared__ int part[1024];
  int t=threadIdx.x;
  int per=(N+1023)/1024; if(per>SCAN_PER) per=SCAN_PER;
  int base=t*per;
  int loc[SCAN_PER];
  int s=0;
  for(int i=0;i<per;i++){ int idx=base+i; int v=(idx<N)? deg[idx]:0; loc[i]=s; s+=v; }
  part[t]=s;
  __syncthreads();
  for(int off=1;off<1024;off<<=1){
    int v=(t>=off)? part[t-off]:0;
    __syncthreads();
    part[t]+=v;
    __syncthreads();
  }
  int ex=(t==0)?0:part[t-1];
  for(int i=0;i<per;i++){
    int idx=base+i;
    if(idx<N){ int r=ex+loc[i]; row[idx]=r; cur[idx]=r; }
  }
  if(t==1023) row[N]=part[1023];
}

__global__ __launch_bounds__(256) void k_fill(
    const int* __restrict__ rcv, int* __restrict__ cur,
    int* __restrict__ eid, int E)
{
  int e=blockIdx.x*256+threadIdx.x;
  if(e>=E) return;
  int pos=atomicAdd(&cur[rcv[e]],1);
  eid[pos]=e;
}

// ---------------- per-edge geometry (receiver-sorted order): SH + radial basis ----------------
__global__ __launch_bounds__(256) void k_edge_setup(
    const float* __restrict__ vec, const int* __restrict__ snd,
    const int* __restrict__ eid, float* __restrict__ Y,
    float* __restrict__ rad, int* __restrict__ snd_s,
    const float* __restrict__ w3, const float* __restrict__ scl, int E)
{
  int j = blockIdx.x*256+threadIdx.x;
  if (j>=E) return;
  int e = eid[j];
  snd_s[j]=snd[e];
  float vx=vec[3*e], vy=vec[3*e+1], vz=vec[3*e+2];
  float r=sqrtf(vx*vx+vy*vy+vz*vz);
  float inv=1.0f/fmaxf(r,1e-9f);
  float y[16];
  y[0]=1.0f;
  const float s3=1.7320508075688772f;
  y[1]=s3*vx*inv; y[2]=s3*vy*inv; y[3]=s3*vz*inv;
  float sc2=scl[0], sc3=scl[1];
  {
    constexpr int O = pathoff(1,1,2);
    #pragma unroll
    for(int c=0;c<5;c++){
      float s=0.f;
      #pragma unroll
      for(int a=0;a<3;a++){
        #pragma unroll
        for(int b=0;b<3;b++){
          if (!msel(a-1,b-1,c-2)) continue;
          s = fmaf(w3[O+(a*3+b)*5+c], y[1+a]*y[1+b], s);
        }
      }
      y[4+c]=sc2*s;
    }
  }
  {
    constexpr int O = pathoff(2,1,3);
    #pragma unroll
    for(int c=0;c<7;c++){
      float s=0.f;
      #pragma unroll
      for(int a=0;a<5;a++){
        #pragma unroll
        for(int b=0;b<3;b++){
          if (!msel(a-2,b-1,c-3)) continue;
          s = fmaf(w3[O+(a*3+b)*7+c], y[4+a]*y[1+b], s);
        }
      }
      y[9+c]=sc3*s;
    }
  }
  float4* Yp=(float4*)(Y+(size_t)j*16);
  Yp[0]=make_float4(y[0],y[1],y[2],y[3]);
  Yp[1]=make_float4(y[4],y[5],y[6],y[7]);
  Yp[2]=make_float4(y[8],y[9],y[10],y[11]);
  Yp[3]=make_float4(y[12],y[13],y[14],y[15]);
  float x = r*0.2f;
  float env=0.f;
  if (x<1.0f){
    float x2=x*x; float x4=x2*x2; float x5=x4*x;
    env = 1.0f - 21.0f*x5 + 35.0f*x5*x - 15.0f*x5*x2;
  }
  const float cb = 0.632455532033675866f; // sqrt(2/5)
  float base = inv*env*cb;
  #pragma unroll
  for(int n=1;n<=8;n++)
    rad[(size_t)j*8 + n-1] = base*sinf(3.14159265358979323846f * x * (float)n);
}

// ---------------- node init: scalar embedding ----------------
__global__ __launch_bounds__(256) void k_node_init(
    const float* __restrict__ embed, const int* __restrict__ z,
    float* __restrict__ feats, int N)
{
  int t = blockIdx.x*256+threadIdx.x;
  int n=t>>5, f=t&31;
  if(n>=N) return;
  float v = embed[z[n]*NF + f];
  float4* p=(float4*)(feats + (size_t)n*512 + f*16);
  p[0]=make_float4(v,0.f,0.f,0.f);
  p[1]=make_float4(0.f,0.f,0.f,0.f);
  p[2]=make_float4(0.f,0.f,0.f,0.f);
  p[3]=make_float4(0.f,0.f,0.f,0.f);
}

// ---------------- per-l channel-mixing linear (optionally per-species weights) ----------------
__global__ __launch_bounds__(256) void k_lin(
    const float* __restrict__ in, float* __restrict__ out,
    const float* __restrict__ w, const int* __restrict__ z, int zstride, int N)
{
  int t=blockIdx.x*256+threadIdx.x;
  int n=t>>5, g=t&31;
  if(n>=N) return;
  const float* wp = w + (z ? (size_t)z[n]*(size_t)zstride : 0);
  const float* ip = in + (size_t)n*512;
  float acc[16];
  #pragma unroll
  for(int c=0;c<16;c++) acc[c]=0.f;
  #pragma unroll 8
  for(int f=0; f<NF; f++){
    const float4* xp = (const float4*)(ip + f*16);
    float4 x0=xp[0], x1=xp[1], x2=xp[2], x3=xp[3];
    float w0v=wp[(f<<5)+g], w1v=wp[1024+(f<<5)+g], w2v=wp[2048+(f<<5)+g], w3v=wp[3072+(f<<5)+g];
    acc[0]  = fmaf(x0.x,w0v,acc[0]);
    acc[1]  = fmaf(x0.y,w1v,acc[1]);
    acc[2]  = fmaf(x0.z,w1v,acc[2]);
    acc[3]  = fmaf(x0.w,w1v,acc[3]);
    acc[4]  = fmaf(x1.x,w2v,acc[4]);
    acc[5]  = fmaf(x1.y,w2v,acc[5]);
    acc[6]  = fmaf(x1.z,w2v,acc[6]);
    acc[7]  = fmaf(x1.w,w2v,acc[7]);
    acc[8]  = fmaf(x2.x,w2v,acc[8]);
    acc[9]  = fmaf(x2.y,w3v,acc[9]);
    acc[10] = fmaf(x2.z,w3v,acc[10]);
    acc[11] = fmaf(x2.w,w3v,acc[11]);
    acc[12] = fmaf(x3.x,w3v,acc[12]);
    acc[13] = fmaf(x3.y,w3v,acc[13]);
    acc[14] = fmaf(x3.z,w3v,acc[14]);
    acc[15] = fmaf(x3.w,w3v,acc[15]);
  }
  float4* op=(float4*)(out + (size_t)n*512 + g*16);
  op[0]=make_float4(acc[0],acc[1],acc[2],acc[3]);
  op[1]=make_float4(acc[4],acc[5],acc[6],acc[7]);
  op[2]=make_float4(acc[8],acc[9],acc[10],acc[11]);
  op[3]=make_float4(acc[12],acc[13],acc[14],acc[15]);
}

// ---------------- radial MLP hidden layers (bf16 output) ----------------
__global__ __launch_bounds__(256) void k_radial(
    const float* __restrict__ rad, const float* __restrict__ w0,
    const float* __restrict__ w1, unsigned short* __restrict__ hid, int E)
{
  __shared__ float w0s[8*64];
  __shared__ float w1s[64*64];
  int tid=threadIdx.x;
  for(int i=tid;i<512;i+=256) w0s[i]=w0[i];
  for(int i=tid;i<4096;i+=256) w1s[i]=w1[i];
  __syncthreads();
  int e=blockIdx.x*256+tid;
  if(e>=E) return;
  const float4* rp=(const float4*)(rad+(size_t)e*8);
  float4 ra=rp[0], rb=rp[1];
  float rv[8]={ra.x,ra.y,ra.z,ra.w,rb.x,rb.y,rb.z,rb.w};
  float h1[64];
  #pragma unroll 8
  for(int j=0;j<64;j++){
    float a=0.f;
    #pragma unroll
    for(int i=0;i<8;i++) a=fmaf(rv[i],w0s[i*64+j],a);
    h1[j]=a/(1.f+__expf(-a));
  }
  unsigned short* hp = hid+(size_t)e*64;
  #pragma unroll 4
  for(int j=0;j<64;j++){
    float a=0.f;
    #pragma unroll
    for(int i=0;i<64;i++) a=fmaf(h1[i],w1s[i*64+j],a);
    hp[j]=f2bf(a/(1.f+__expf(-a)));
  }
}

// ---------------- cast+transpose w2 [64 x 1088] -> w2t [1088 x 64] bf16 ----------------
__global__ __launch_bounds__(256) void k_cast_w2t(
    const float* __restrict__ w2, unsigned short* __restrict__ w2t)
{
  int t=blockIdx.x*256+threadIdx.x;
  if(t>=1088*64) return;
  int c=t>>6, k=t&63;
  w2t[(size_t)c*64+k]=f2bf(w2[(size_t)k*1088+c]);
}

// ---------------- rw GEMM via MFMA: C[rows x ncols](bf16, row-major) = A[rows x 64](bf16) * Bt^T ----------------
// Bt is [ncolsTotal x 64] bf16 (transposed weights). Layouts (HW-verified m89/m120):
//   A-frag: A[m=lane&15][k=quad*8+j];  B-frag: B[k=quad*8+j][n=lane&15];
//   D: row(M)=quad*4+reg, col(N)=lane&15.
__global__ __launch_bounds__(256) void k_gemm_mfma(
    const unsigned short* __restrict__ A, const unsigned short* __restrict__ Bt,
    unsigned short* __restrict__ C, int ldc, int ncols)
{
  int wave = threadIdx.x>>6;
  int lane = threadIdx.x&63;
  int m16 = lane&15, quad = lane>>4;
  size_t rowbase = (size_t)blockIdx.y*64;
  int col0 = blockIdx.x*128 + wave*32;
  f32x4 acc[4][2];
  #pragma unroll
  for(int mt=0;mt<4;mt++){
    #pragma unroll
    for(int nt=0;nt<2;nt++) acc[mt][nt]=(f32x4){0.f,0.f,0.f,0.f};
  }
  #pragma unroll
  for(int ks=0;ks<2;ks++){
    bf16x8 a[4], b[2];
    #pragma unroll
    for(int mt=0;mt<4;mt++)
      a[mt] = *(const bf16x8*)(A + (rowbase+mt*16+m16)*64 + ks*32 + quad*8);
    #pragma unroll
    for(int nt=0;nt<2;nt++){
      int c = col0 + nt*16 + m16;
      if (c<ncols) b[nt] = *(const bf16x8*)(Bt + (size_t)c*64 + ks*32 + quad*8);
      else         b[nt] = (bf16x8){0,0,0,0,0,0,0,0};
    }
    #pragma unroll
    for(int mt=0;mt<4;mt++){
      #pragma unroll
      for(int nt=0;nt<2;nt++)
        acc[mt][nt]=__builtin_amdgcn_mfma_f32_16x16x32_bf16(a[mt],b[nt],acc[mt][nt],0,0,0);
    }
  }
  #pragma unroll
  for(int mt=0;mt<4;mt++){
    #pragma unroll
    for(int nt=0;nt<2;nt++){
      int c = col0 + nt*16 + m16;
      if (c>=ncols) continue;
      #pragma unroll
      for(int r=0;r<4;r++){
        size_t row = rowbase + mt*16 + quad*4 + r;
        C[row*(size_t)ldc + c] = f2bf(acc[mt][nt][r]);
      }
    }
  }
}

// ---------------- edge tensor product -> per-edge messages (receiver-sorted) ----------------
// rw: [edge][col] bf16 row-major (col = p*32+f). Block = 8 edges x 32 f; rw rows
// staged via LDS (coalesced 16B global loads, then ds_read_u16 per path).
template<bool L0>
__global__ __launch_bounds__(256) void k_tp_msg(
    const float* __restrict__ hlin, const float* __restrict__ Y,
    const unsigned short* __restrict__ rw, const int* __restrict__ snd_s,
    const float* __restrict__ w3, unsigned short* __restrict__ msgs,
    int eb, int ecnt)
{
  constexpr int RWLD = L0 ? 128 : 1088;
  constexpr int LSTR = L0 ? 160 : 1120;   // shorts; 2*LSTR bytes = 16-bank shift between edges
  constexpr int VL = RWLD/8;
  __shared__ unsigned short rws[8*LSTR];
  int el0 = blockIdx.x*8;
  {
    int tid=threadIdx.x;
    for(int i=tid;i<8*VL;i+=256){
      int e=i/VL, v=i-e*VL;
      int elg=el0+e;
      bf16x8 val;
      if(elg<ecnt) val=*(const bf16x8*)(rw+(size_t)elg*RWLD+v*8);
      else         val=(bf16x8){0,0,0,0,0,0,0,0};
      *(bf16x8*)(&rws[e*LSTR+v*8])=val;
    }
  }
  __syncthreads();
  int le=threadIdx.x>>5, f=threadIdx.x&31;
  int el=el0+le;
  if(el>=ecnt) return;
  int j=eb+el;
  int s=snd_s[j];
  float hs[16];
  {
    const float* hp = hlin+(size_t)s*512+f*16;
    if (L0){
      hs[0]=hp[0];
      #pragma unroll
      for(int c=1;c<16;c++) hs[c]=0.f;
    } else {
      const float4* hv=(const float4*)hp;
      float4 a=hv[0],b=hv[1],cc=hv[2],d=hv[3];
      hs[0]=a.x; hs[1]=a.y; hs[2]=a.z; hs[3]=a.w;
      hs[4]=b.x; hs[5]=b.y; hs[6]=b.z; hs[7]=b.w;
      hs[8]=cc.x; hs[9]=cc.y; hs[10]=cc.z; hs[11]=cc.w;
      hs[12]=d.x; hs[13]=d.y; hs[14]=d.z; hs[15]=d.w;
    }
  }
  float yv[16];
  {
    const float4* yp=(const float4*)(Y+(size_t)j*16);
    float4 a=yp[0],b=yp[1],cc=yp[2],d=yp[3];
    yv[0]=a.x; yv[1]=a.y; yv[2]=a.z; yv[3]=a.w;
    yv[4]=b.x; yv[5]=b.y; yv[6]=b.z; yv[7]=b.w;
    yv[8]=cc.x; yv[9]=cc.y; yv[10]=cc.z; yv[11]=cc.w;
    yv[12]=d.x; yv[13]=d.y; yv[14]=d.z; yv[15]=d.w;
  }
  const unsigned short* rp = rws + le*LSTR + f;
  float acc[16];
  #pragma unroll
  for(int c=0;c<16;c++) acc[c]=0.f;
  #pragma unroll
  for(int p=0;p<NPATHS;p++){
    const int l1=PT.l1[p], l2=PT.l2[p], l3=PT.l3[p], off=PT.off[p];
    if (L0 && l1!=0) continue;
    const float rv=bf2f(rp[p*32]);
    #pragma unroll
    for(int a=0;a<2*l1+1;a++){
      const float ha=hs[l1*l1+a];
      #pragma unroll
      for(int b=0;b<2*l2+1;b++){
        const float tt=ha*yv[l2*l2+b]*rv;
        #pragma unroll
        for(int c=0;c<2*l3+1;c++){
          if (!msel(a-l1,b-l2,c-l3)) continue;
          acc[l3*l3+c]=fmaf(w3[off+(a*(2*l2+1)+b)*(2*l3+1)+c],tt,acc[l3*l3+c]);
        }
      }
    }
  }
  bf16x8 m0, m1;
  #pragma unroll
  for(int c=0;c<8;c++){
    m0[c]=(short)f2bf(acc[c]*0.0625f);
    m1[c]=(short)f2bf(acc[8+c]*0.0625f);
  }
  bf16x8* mp=(bf16x8*)(msgs+(size_t)el*512+f*16);
  mp[0]=m0; mp[1]=m1;
}

// ---------------- CSR segment-sum of bf16 messages (no atomics) ----------------
__global__ __launch_bounds__(256) void k_seg_sum(
    const unsigned short* __restrict__ msgs, const int* __restrict__ row,
    float* __restrict__ agg, int eb, int ecnt, int N)
{
  int t=blockIdx.x*256+threadIdx.x;
  int n=t>>6, q=t&63;            // q indexes 8 consecutive floats; wave = 1 node
  if(n>=N) return;
  int lo=row[n], hi=row[n+1];
  int a0 = lo>eb ? lo : eb;
  int a1e = eb+ecnt;
  int a1 = hi<a1e ? hi : a1e;
  if(a0>=a1) return;
  float s[8];
  #pragma unroll
  for(int i=0;i<8;i++) s[i]=0.f;
  for(int j=a0;j<a1;j++){
    bf16x8 v=*(const bf16x8*)(msgs+(size_t)(j-eb)*512+q*8);
    #pragma unroll
    for(int i=0;i<8;i++) s[i]+=bf2f((unsigned short)v[i]);
  }
  float* ap=agg+(size_t)n*512+q*8;
  float4* a0p=(float4*)ap;
  float4 o0=a0p[0], o1=a0p[1];
  o0.x+=s[0]; o0.y+=s[1]; o0.z+=s[2]; o0.w+=s[3];
  o1.x+=s[4]; o1.y+=s[5]; o1.z+=s[6]; o1.w+=s[7];
  a0p[0]=o0; a0p[1]=o1;
}

// ---------------- node-wise symmetric tensor product (product basis) ----------------
__device__ __forceinline__ void tp_pair(const float* __restrict__ w3n,
    const float* __restrict__ x, const float* __restrict__ yy, float* __restrict__ o)
{
  #pragma unroll
  for(int p=0;p<NPATHS;p++){
    const int l1=PT.l1[p], l2=PT.l2[p], l3=PT.l3[p], off=PT.off[p];
    #pragma unroll
    for(int a=0;a<2*l1+1;a++){
      const float xa=x[l1*l1+a];
      #pragma unroll
      for(int b=0;b<2*l2+1;b++){
        const float tt=xa*yy[l2*l2+b];
        #pragma unroll
        for(int c=0;c<2*l3+1;c++){
          if(!msel(a-l1,b-l2,c-l3)) continue;
          o[l3*l3+c]=fmaf(w3n[off+(a*(2*l2+1)+b)*(2*l3+1)+c],tt,o[l3*l3+c]);
        }
      }
    }
  }
}

__global__ __launch_bounds__(256) void k_tp_node(
    const float* __restrict__ in, float* __restrict__ out,
    const float* __restrict__ w3n, const float* __restrict__ pb,
    const int* __restrict__ z, int N)
{
  int t=blockIdx.x*256+threadIdx.x;
  int n=t>>5, f=t&31;
  if(n>=N) return;
  float A[16];
  {
    const float4* p=(const float4*)(in+(size_t)n*512+f*16);
    float4 a=p[0],b=p[1],c=p[2],d=p[3];
    A[0]=a.x; A[1]=a.y; A[2]=a.z; A[3]=a.w;
    A[4]=b.x; A[5]=b.y; A[6]=b.z; A[7]=b.w;
    A[8]=c.x; A[9]=c.y; A[10]=c.z; A[11]=c.w;
    A[12]=d.x; A[13]=d.y; A[14]=d.z; A[15]=d.w;
  }
  float B2[16]; float B3[16];
  #pragma unroll
  for(int c=0;c<16;c++){ B2[c]=0.f; B3[c]=0.f; }
  tp_pair(w3n, A, A, B2);
  tp_pair(w3n, B2, A, B3);
  int zz=z[n];
  float wa=pb[zz*96+f], wb=pb[zz*96+32+f], wc=pb[zz*96+64+f];
  float o[16];
  #pragma unroll
  for(int c=0;c<16;c++) o[c]=wa*A[c]+wb*B2[c]+wc*B3[c];
  float4* op=(float4*)(out+(size_t)n*512+f*16);
  op[0]=make_float4(o[0],o[1],o[2],o[3]);
  op[1]=make_float4(o[4],o[5],o[6],o[7]);
  op[2]=make_float4(o[8],o[9],o[10],o[11]);
  op[3]=make_float4(o[12],o[13],o[14],o[15]);
}

// ---------------- readouts ----------------
__global__ __launch_bounds__(256) void k_resid(
    const float* __restrict__ feats, const float* __restrict__ res1,
    const int* __restrict__ z, float* __restrict__ resid, int N)
{
  int t=blockIdx.x*256+threadIdx.x;
  int n=t>>5, g=t&31;
  if(n>=N) return;
  const float* wp=res1+(size_t)z[n]*1024;
  float a=0.f;
  #pragma unroll 8
  for(int f=0;f<32;f++) a=fmaf(feats[(size_t)n*512+f*16], wp[(f<<5)+g], a);
  resid[(size_t)n*32+g]=a;
}

__global__ __launch_bounds__(256) void k_e0(
    const float* __restrict__ feats, const float* __restrict__ ro0,
    float* __restrict__ e0, int N)
{
  int n=blockIdx.x*256+threadIdx.x;
  if(n>=N) return;
  float a=0.f;
  #pragma unroll 8
  for(int f=0;f<32;f++) a=fmaf(feats[(size_t)n*512+f*16], ro0[f], a);
  e0[n]=a;
}

__global__ __launch_bounds__(256) void k_final(
    const float* __restrict__ h, const float* __restrict__ resid,
    const float* __restrict__ e0a, const float* __restrict__ ro1a,
    const float* __restrict__ ro1b, float* __restrict__ out, int N)
{
  int t=blockIdx.x*256+threadIdx.x;
  float val=0.f;
  if (t<N){
    float sc[32];
    #pragma unroll 8
    for(int f=0;f<32;f++) sc[f]=h[(size_t)t*512+f*16]+resid[(size_t)t*32+f];
    float e1=0.f;
    #pragma unroll
    for(int j=0;j<16;j++){
      float a=0.f;
      #pragma unroll
      for(int f=0;f<32;f++) a=fmaf(sc[f],ro1a[f*16+j],a);
      float s=a/(1.f+__expf(-a));
      e1=fmaf(s,ro1b[j],e1);
    }
    val = -1.5f + 2.0f*(e0a[t]+e1) - 10.0f;
  }
  __shared__ float red[256];
  red[threadIdx.x]=val;
  __syncthreads();
  for(int s=128;s>0;s>>=1){
    if(threadIdx.x<s) red[threadIdx.x]+=red[threadIdx.x+s];
    __syncthreads();
  }
  if(threadIdx.x==0) atomicAdd(out, red[0]);
}

// ---------------- host orchestration ----------------
extern "C" void kernel_launch(void* const* d_in, const int* in_sizes, int n_in,
                              void* d_out, int out_size, void* d_ws, size_t ws_size,
                              hipStream_t stream)
{
  const float* vec   =(const float*)d_in[0];
  const int*   zarr  =(const int*)  d_in[1];
  const int*   snd   =(const int*)  d_in[2];
  const int*   rcv   =(const int*)  d_in[3];
  const float* embed =(const float*)d_in[4];
  const float* r0w0  =(const float*)d_in[5];
  const float* r0w1  =(const float*)d_in[6];
  const float* r0w2  =(const float*)d_in[7];
  const float* up0   =(const float*)d_in[8];
  const float* post0 =(const float*)d_in[9];
  const float* pb0   =(const float*)d_in[10];
  const float* pblin0=(const float*)d_in[11];
  const float* r1w0  =(const float*)d_in[12];
  const float* r1w1  =(const float*)d_in[13];
  const float* r1w2  =(const float*)d_in[14];
  const float* up1   =(const float*)d_in[15];
  const float* post1 =(const float*)d_in[16];
  const float* pb1   =(const float*)d_in[17];
  const float* pblin1=(const float*)d_in[18];
  const float* sel0  =(const float*)d_in[19];
  const float* ro0   =(const float*)d_in[20];
  const float* res1  =(const float*)d_in[21];
  const float* ro1a  =(const float*)d_in[22];
  const float* ro1b  =(const float*)d_in[23];

  const int E = in_sizes[0]/3;
  const int N = in_sizes[1];
  const int Epad = (E+63)&~63;

  char* ws=(char*)d_ws;
  size_t o=0;
  auto alloc=[&](size_t bytes)->char*{
    char* p=ws+o;
    o=(o+bytes+255)&~(size_t)255;
    return p;
  };
  float* w3jd =(float*)alloc((size_t)W3JTOT*4);
  float* w3jn =(float*)alloc((size_t)W3JTOT*4);
  float* scl  =(float*)alloc(8);
  int*   deg  =(int*)  alloc((size_t)N*4);
  int*   rowp =(int*)  alloc((size_t)(N+1)*4);
  int*   cur  =(int*)  alloc((size_t)N*4);
  int*   eid  =(int*)  alloc((size_t)E*4);
  int*   snd_s=(int*)  alloc((size_t)E*4);
  float* Yb   =(float*)alloc((size_t)E*16*4);
  float* radb =(float*)alloc((size_t)E*8*4);
  unsigned short* hidb=(unsigned short*)alloc((size_t)Epad*64*2);
  unsigned short* w2t0=(unsigned short*)alloc((size_t)1088*64*2);
  unsigned short* w2t1=(unsigned short*)alloc((size_t)1088*64*2);
  float* feats=(float*)alloc((size_t)N*512*4);
  float* bufA =(float*)alloc((size_t)N*512*4);
  float* bufB =(float*)alloc((size_t)N*512*4);
  float* bufC =(float*)alloc((size_t)N*512*4);
  float* e0b  =(float*)alloc((size_t)N*4);
  float* residb=(float*)alloc((size_t)N*32*4);
  char*  dyn  = ws+o;
  size_t remain = ws_size>o ? ws_size-o : 0;

  dim3 tb(256);
  dim3 nblk((unsigned)((N*32+255)/256));
  dim3 eblk((unsigned)((E+255)/256));
  dim3 qblk((unsigned)((N*64+255)/256));

  k_init_w3j<<<dim3((W3JTOT+255)/256),tb,0,stream>>>(w3jd,w3jn);
  k_init_scales<<<dim3(1),dim3(64),0,stream>>>(w3jd,scl);

  // CSR build (receiver-sorted edge order)
  hipMemsetAsync(deg,0,(size_t)N*4,stream);
  k_count<<<eblk,tb,0,stream>>>(rcv,deg,E);
  k_scan<<<dim3(1),dim3(1024),0,stream>>>(deg,rowp,cur,N);
  k_fill<<<eblk,tb,0,stream>>>(rcv,cur,eid,E);

  k_edge_setup<<<eblk,tb,0,stream>>>(vec,snd,eid,Yb,radb,snd_s,w3jd,scl,E);
  k_node_init<<<nblk,tb,0,stream>>>(embed,zarr,feats,N);

  // cast+transpose radial-MLP final weights to bf16 (per launch)
  k_cast_w2t<<<dim3((1088*64+255)/256),tb,0,stream>>>(r0w2,w2t0);
  k_cast_w2t<<<dim3((1088*64+255)/256),tb,0,stream>>>(r1w2,w2t1);

  auto run_edges=[&](bool l0, const float* hlin, const unsigned short* w2t, float* agg){
    const int rwld = l0?128:1088;
    size_t per = (size_t)rwld*2 + 1024;      // rw(bf16, row-major) + msgs(bf16) per edge
    long rows = (long)(remain/per);
    rows -= rows%64;
    if (rows>(long)Epad) rows=Epad;
    if (rows<64) rows=64;
    unsigned short* rwb = (unsigned short*)dyn;
    unsigned short* msgsb = (unsigned short*)(dyn + (((size_t)rows*(size_t)rwld*2 + 255)&~(size_t)255));
    for(long eb=0;eb<E;eb+=rows){
      long cnt = E-eb; if(cnt>rows) cnt=rows;
      long cntp = (cnt+63)&~63L;
      dim3 g((unsigned)((rwld+127)/128),(unsigned)(cntp/64));
      k_gemm_mfma<<<g,tb,0,stream>>>(hidb+(size_t)eb*64, w2t, rwb, rwld, rwld);
      dim3 g2((unsigned)((cnt+7)/8));
      if(l0) k_tp_msg<true ><<<g2,tb,0,stream>>>(hlin,Yb,rwb,snd_s,w3jd,msgsb,(int)eb,(int)cnt);
      else   k_tp_msg<false><<<g2,tb,0,stream>>>(hlin,Yb,rwb,snd_s,w3jd,msgsb,(int)eb,(int)cnt);
      k_seg_sum<<<qblk,tb,0,stream>>>(msgsb,rowp,agg,(int)eb,(int)cnt,N);
    }
  };

  // ---- layer 0 ----
  k_lin<<<nblk,tb,0,stream>>>(feats,bufA,up0,(const int*)nullptr,0,N);
  k_radial<<<eblk,tb,0,stream>>>(radb,r0w0,r0w1,hidb,E);
  hipMemsetAsync(bufB,0,(size_t)N*512*4,stream);
  run_edges(true,bufA,w2t0,bufB);
  k_lin<<<nblk,tb,0,stream>>>(bufB,bufC,post0,(const int*)nullptr,0,N);
  k_lin<<<nblk,tb,0,stream>>>(bufC,bufA,sel0,zarr,4096,N);
  k_tp_node<<<nblk,tb,0,stream>>>(bufA,bufB,w3jn,pb0,zarr,N);
  k_lin<<<nblk,tb,0,stream>>>(bufB,feats,pblin0,(const int*)nullptr,0,N);
  k_e0<<<dim3((N+255)/256),tb,0,stream>>>(feats,ro0,e0b,N);
  k_resid<<<nblk,tb,0,stream>>>(feats,res1,zarr,residb,N);

  // ---- layer 1 ----
  k_lin<<<nblk,tb,0,stream>>>(feats,bufA,up1,(const int*)nullptr,0,N);
  k_radial<<<eblk,tb,0,stream>>>(radb,r1w0,r1w1,hidb,E);
  hipMemsetAsync(bufC,0,(size_t)N*512*4,stream);
  run_edges(false,bufA,w2t1,bufC);
  k_lin<<<nblk,tb,0,stream>>>(bufC,bufB,post1,(const int*)nullptr,0,N);
  k_tp_node<<<nblk,tb,0,stream>>>(bufB,bufA,w3jn,pb1,zarr,N);
  k_lin<<<nblk,tb,0,stream>>>(bufA,bufC,pblin1,(const int*)nullptr,0,N);

  hipMemsetAsync(d_out,0,4,stream);
  k_final<<<dim3((N+255)/256),tb,0,stream>>>(bufC,residb,e0b,ro1a,ro1b,(float*)d_out,N);
}

// Round 8
// 1213.675 us; speedup vs baseline: 2.4600x; 1.6709x over previous
//
#include <hip/hip_runtime.h>
#include <math.h>

// ---------------- static config ----------------
#define NF 32
#define NPATHS 34

typedef __attribute__((ext_vector_type(8))) short bf16x8;
typedef __attribute__((ext_vector_type(4))) float f32x4;

__device__ __forceinline__ unsigned short f2bf(float v){
  unsigned u = __float_as_uint(v);
  u += 0x7fffu + ((u>>16)&1u);
  return (unsigned short)(u>>16);
}
__device__ __forceinline__ float bf2f(unsigned short h){
  return __uint_as_float(((unsigned)h)<<16);
}

struct PathTab { int l1[NPATHS]; int l2[NPATHS]; int l3[NPATHS]; };
constexpr PathTab mkpaths(){
  PathTab t{}; int n=0;
  for(int a=0;a<=3;a++)for(int b=0;b<=3;b++)for(int c=0;c<=3;c++){
    int lo = a>b ? a-b : b-a;
    if(c>=lo && c<=a+b){ t.l1[n]=a; t.l2[n]=b; t.l3[n]=c; n++; }
  }
  return t;
}
constexpr PathTab PT = mkpaths();

// ---------------- compile-time Wigner-3j (exact replica of reference math) ----------------
struct FactT { double v[22]; };
constexpr FactT mkfactT(){ FactT f{}; f.v[0]=1.0; for(int i=1;i<22;i++) f.v[i]=f.v[i-1]*(double)i; return f; }
constexpr FactT FT = mkfactT();
constexpr double cfact(int n){ return FT.v[n]; }

constexpr double csqrt(double x){
  if(x<=0.0) return 0.0;
  double g = x<1.0 ? 1.0 : x;
  for(int i=0;i<40;i++) g=0.5*(g+x/g);
  return g;
}

constexpr double su2cg(int j1,int j2,int j3,int m1,int m2){
  int m3=m1+m2;
  if(m3<-j3||m3>j3) return 0.0;
  double pref = (double)(2*j3+1)*cfact(j3+j1-j2)*cfact(j3-j1+j2)*cfact(j1+j2-j3)/cfact(j1+j2+j3+1);
  pref *= cfact(j3+m3)*cfact(j3-m3)*cfact(j1-m1)*cfact(j1+m1)*cfact(j2-m2)*cfact(j2+m2);
  pref = csqrt(pref);
  int k0=0; if(j2-j3-m1>k0)k0=j2-j3-m1; if(j1-j3+m2>k0)k0=j1-j3+m2;
  int k1=j1+j2-j3; if(j1-m1<k1)k1=j1-m1; if(j2+m2<k1)k1=j2+m2;
  double s=0.0;
  for(int k=k0;k<=k1;k++){
    double d = cfact(k)*cfact(j1+j2-j3-k)*cfact(j1-m1-k)*cfact(j2+m2-k)*cfact(j3-j2+m1+k)*cfact(j3-j1-m2+k);
    s += (k&1)? -1.0/d : 1.0/d;
  }
  return pref*s;
}

struct ccd { double x, y; };
constexpr ccd cqval(int l,int r,int col){
  const double is2 = 0.70710678118654752440;
  double re=0.0, im=0.0;
  if (r<l){ if (col==2*l-r) re=is2; else if (col==r) im=-is2; }
  else if (r==l){ if (col==l) re=1.0; }
  else { double s = ((r-l)&1)? -1.0:1.0;
         if (col==r) re=s*is2; else if (col==2*l-r) im=s*is2; }
  ccd v{re,im};
  switch(l&3){           // multiply by (-i)^l
    case 1: return ccd{ v.y, -v.x };
    case 2: return ccd{-v.x, -v.y };
    case 3: return ccd{-v.y,  v.x };
    default: return v;
  }
}

constexpr double w3entry(int l1,int l2,int l3,int i,int j,int k){
  double re=0.0;
  for(int a=0;a<2*l1+1;a++){
    ccd qa=cqval(l1,a,i); if(qa.x==0.0&&qa.y==0.0) continue;
    for(int b=0;b<2*l2+1;b++){
      ccd qb=cqval(l2,b,j); if(qb.x==0.0&&qb.y==0.0) continue;
      int m1=a-l1, m2=b-l2, m3=m1+m2;
      if(m3<-l3||m3>l3) continue;
      int c=m3+l3;
      double cg=su2cg(l1,l2,l3,m1,m2); if(cg==0.0) continue;
      ccd qc=cqval(l3,c,k); qc.y=-qc.y;   // conj
      if(qc.x==0.0&&qc.y==0.0) continue;
      ccd ab{qa.x*qb.x-qa.y*qb.y, qa.x*qb.y+qa.y*qb.x};
      re += cg*(ab.x*qc.x - ab.y*qc.y);
    }
  }
  return re;
}

template<int L1,int L2,int L3> struct W3Arr { float v[(2*L1+1)*(2*L2+1)*(2*L3+1)]; };
template<int L1,int L2,int L3> constexpr W3Arr<L1,L2,L3> mkW3(double scale){
  W3Arr<L1,L2,L3> r{};
  for(int i=0;i<2*L1+1;i++)
    for(int j=0;j<2*L2+1;j++)
      for(int k=0;k<2*L3+1;k++)
        r.v[(i*(2*L2+1)+j)*(2*L3+1)+k] = (float)(w3entry(L1,L2,L3,i,j,k)*scale);
  return r;
}
template<int L1,int L2,int L3> constexpr W3Arr<L1,L2,L3> W3V = mkW3<L1,L2,L3>(1.0);
template<int L1,int L2,int L3> constexpr W3Arr<L1,L2,L3> W3N = mkW3<L1,L2,L3>(1.0/csqrt(2.0*L3+1.0));

// SH recursion scales (replica of reference _sh_scales, float64 like numpy)
struct SCt { double sc2, sc3; };
constexpr SCt mksc(){
  double v0=0.2,v1=-0.6,v2=0.7;
  double nv=csqrt(v0*v0+v1*v1+v2*v2);
  double s3=csqrt(3.0);
  double y1[3]={s3*v0/nv, s3*v1/nv, s3*v2/nv};
  double t2[5]={0,0,0,0,0}; double n2=0.0;
  for(int c=0;c<5;c++){
    double s=0.0;
    for(int a=0;a<3;a++)for(int b=0;b<3;b++) s += w3entry(1,1,2,a,b,c)*y1[a]*y1[b];
    t2[c]=s; n2+=s*s;
  }
  double sc2=csqrt(5.0)/csqrt(n2);
  double y2[5]={sc2*t2[0],sc2*t2[1],sc2*t2[2],sc2*t2[3],sc2*t2[4]};
  double n3=0.0;
  for(int c=0;c<7;c++){
    double s=0.0;
    for(int a=0;a<5;a++)for(int b=0;b<3;b++) s += w3entry(2,1,3,a,b,c)*y2[a]*y1[b];
    n3+=s*s;
  }
  double sc3=csqrt(7.0)/csqrt(n3);
  return SCt{sc2,sc3};
}
constexpr SCt SCV = mksc();

// ---------------- template-unrolled TP with literal W3J, true-zero elision ----------------
template<bool NORM,int l1,int l2,int l3,int A,int B,int C>
__device__ __forceinline__ void w3term(const float* __restrict__ x, const float* __restrict__ y,
                                       float rv, float* __restrict__ acc){
  constexpr float w = NORM ? W3N<l1,l2,l3>.v[(A*(2*l2+1)+B)*(2*l3+1)+C]
                           : W3V<l1,l2,l3>.v[(A*(2*l2+1)+B)*(2*l3+1)+C];
  if constexpr (w!=0.0f)
    acc[l3*l3+C] = fmaf(w, x[l1*l1+A]*y[l2*l2+B]*rv, acc[l3*l3+C]);
}
template<bool NORM,int l1,int l2,int l3,int A,int B,int C>
__device__ __forceinline__ void w3loopC(const float* x,const float* y,float rv,float* acc){
  if constexpr (C<2*l3+1){
    w3term<NORM,l1,l2,l3,A,B,C>(x,y,rv,acc);
    w3loopC<NORM,l1,l2,l3,A,B,C+1>(x,y,rv,acc);
  }
}
template<bool NORM,int l1,int l2,int l3,int A,int B>
__device__ __forceinline__ void w3loopB(const float* x,const float* y,float rv,float* acc){
  if constexpr (B<2*l2+1){
    w3loopC<NORM,l1,l2,l3,A,B,0>(x,y,rv,acc);
    w3loopB<NORM,l1,l2,l3,A,B+1>(x,y,rv,acc);
  }
}
template<bool NORM,int l1,int l2,int l3,int A>
__device__ __forceinline__ void w3loopA(const float* x,const float* y,float rv,float* acc){
  if constexpr (A<2*l1+1){
    w3loopB<NORM,l1,l2,l3,A,0>(x,y,rv,acc);
    w3loopA<NORM,l1,l2,l3,A+1>(x,y,rv,acc);
  }
}

template<bool L0,int P>
__device__ __forceinline__ void tp_paths(const float* hs,const float* yv,
                                         const unsigned short* rp, float* acc){
  if constexpr (P<NPATHS){
    constexpr int l1=PT.l1[P], l2=PT.l2[P], l3=PT.l3[P];
    if constexpr (!(L0 && l1!=0)){
      float rv = bf2f(rp[P*32]);
      w3loopA<false,l1,l2,l3,0>(hs,yv,rv,acc);
    }
    tp_paths<L0,P+1>(hs,yv,rp,acc);
  }
}

template<int P>
__device__ __forceinline__ void tpn_paths(const float* x,const float* y,float* o){
  if constexpr (P<NPATHS){
    constexpr int l1=PT.l1[P], l2=PT.l2[P], l3=PT.l3[P];
    w3loopA<true,l1,l2,l3,0>(x,y,1.0f,o);
    tpn_paths<P+1>(x,y,o);
  }
}

// ---------------- CSR build: degree count, scan, fill ----------------
__global__ __launch_bounds__(256) void k_count(
    const int* __restrict__ rcv, int* __restrict__ deg, int E)
{
  int e=blockIdx.x*256+threadIdx.x;
  if(e>=E) return;
  atomicAdd(&deg[rcv[e]],1);
}

#define SCAN_PER 32
__global__ __launch_bounds__(1024) void k_scan(
    const int* __restrict__ deg, int* __restrict__ row,
    int* __restrict__ cur, int N)
{
  __shared__ int part[1024];
  int t=threadIdx.x;
  int per=(N+1023)/1024; if(per>SCAN_PER) per=SCAN_PER;
  int base=t*per;
  int loc[SCAN_PER];
  int s=0;
  for(int i=0;i<per;i++){ int idx=base+i; int v=(idx<N)? deg[idx]:0; loc[i]=s; s+=v; }
  part[t]=s;
  __syncthreads();
  for(int off=1;off<1024;off<<=1){
    int v=(t>=off)? part[t-off]:0;
    __syncthreads();
    part[t]+=v;
    __syncthreads();
  }
  int ex=(t==0)?0:part[t-1];
  for(int i=0;i<per;i++){
    int idx=base+i;
    if(idx<N){ int r=ex+loc[i]; row[idx]=r; cur[idx]=r; }
  }
  if(t==1023) row[N]=part[1023];
}

__global__ __launch_bounds__(256) void k_fill(
    const int* __restrict__ rcv, int* __restrict__ cur,
    int* __restrict__ eid, int E)
{
  int e=blockIdx.x*256+threadIdx.x;
  if(e>=E) return;
  int pos=atomicAdd(&cur[rcv[e]],1);
  eid[pos]=e;
}

// ---------------- per-edge geometry (receiver-sorted order): SH + radial basis ----------------
__global__ __launch_bounds__(256) void k_edge_setup(
    const float* __restrict__ vec, const int* __restrict__ snd,
    const int* __restrict__ eid, float* __restrict__ Y,
    float* __restrict__ rad, int* __restrict__ snd_s, int E)
{
  int j = blockIdx.x*256+threadIdx.x;
  if (j>=E) return;
  int e = eid[j];
  snd_s[j]=snd[e];
  float vx=vec[3*e], vy=vec[3*e+1], vz=vec[3*e+2];
  float r=sqrtf(vx*vx+vy*vy+vz*vz);
  float inv=1.0f/fmaxf(r,1e-9f);
  float y[16];
  y[0]=1.0f;
  const float s3=1.7320508075688772f;
  y[1]=s3*vx*inv; y[2]=s3*vy*inv; y[3]=s3*vz*inv;
  constexpr float sc2=(float)SCV.sc2, sc3=(float)SCV.sc3;
  {
    float t[16];
    #pragma unroll
    for(int c=0;c<16;c++) t[c]=0.f;
    w3loopA<false,1,1,2,0>(y,y,1.0f,t);     // t[4..8] = einsum(w112, y1, y1)
    #pragma unroll
    for(int c=0;c<5;c++) y[4+c]=sc2*t[4+c];
    w3loopA<false,2,1,3,0>(y,y,1.0f,t);     // t[9..15] = einsum(w213, y2, y1)
    #pragma unroll
    for(int c=0;c<7;c++) y[9+c]=sc3*t[9+c];
  }
  float4* Yp=(float4*)(Y+(size_t)j*16);
  Yp[0]=make_float4(y[0],y[1],y[2],y[3]);
  Yp[1]=make_float4(y[4],y[5],y[6],y[7]);
  Yp[2]=make_float4(y[8],y[9],y[10],y[11]);
  Yp[3]=make_float4(y[12],y[13],y[14],y[15]);
  float x = r*0.2f;
  float env=0.f;
  if (x<1.0f){
    float x2=x*x; float x4=x2*x2; float x5=x4*x;
    env = 1.0f - 21.0f*x5 + 35.0f*x5*x - 15.0f*x5*x2;
  }
  const float cb = 0.632455532033675866f; // sqrt(2/5)
  float base = inv*env*cb;
  #pragma unroll
  for(int n=1;n<=8;n++)
    rad[(size_t)j*8 + n-1] = base*sinf(3.14159265358979323846f * x * (float)n);
}

// ---------------- node init: scalar embedding ----------------
__global__ __launch_bounds__(256) void k_node_init(
    const float* __restrict__ embed, const int* __restrict__ z,
    float* __restrict__ feats, int N)
{
  int t = blockIdx.x*256+threadIdx.x;
  int n=t>>5, f=t&31;
  if(n>=N) return;
  float v = embed[z[n]*NF + f];
  float4* p=(float4*)(feats + (size_t)n*512 + f*16);
  p[0]=make_float4(v,0.f,0.f,0.f);
  p[1]=make_float4(0.f,0.f,0.f,0.f);
  p[2]=make_float4(0.f,0.f,0.f,0.f);
  p[3]=make_float4(0.f,0.f,0.f,0.f);
}

// ---------------- per-l channel-mixing linear (optionally per-species weights) ----------------
__global__ __launch_bounds__(256) void k_lin(
    const float* __restrict__ in, float* __restrict__ out,
    const float* __restrict__ w, const int* __restrict__ z, int zstride, int N)
{
  int t=blockIdx.x*256+threadIdx.x;
  int n=t>>5, g=t&31;
  if(n>=N) return;
  const float* wp = w + (z ? (size_t)z[n]*(size_t)zstride : 0);
  const float* ip = in + (size_t)n*512;
  float acc[16];
  #pragma unroll
  for(int c=0;c<16;c++) acc[c]=0.f;
  #pragma unroll 8
  for(int f=0; f<NF; f++){
    const float4* xp = (const float4*)(ip + f*16);
    float4 x0=xp[0], x1=xp[1], x2=xp[2], x3=xp[3];
    float w0v=wp[(f<<5)+g], w1v=wp[1024+(f<<5)+g], w2v=wp[2048+(f<<5)+g], w3v=wp[3072+(f<<5)+g];
    acc[0]  = fmaf(x0.x,w0v,acc[0]);
    acc[1]  = fmaf(x0.y,w1v,acc[1]);
    acc[2]  = fmaf(x0.z,w1v,acc[2]);
    acc[3]  = fmaf(x0.w,w1v,acc[3]);
    acc[4]  = fmaf(x1.x,w2v,acc[4]);
    acc[5]  = fmaf(x1.y,w2v,acc[5]);
    acc[6]  = fmaf(x1.z,w2v,acc[6]);
    acc[7]  = fmaf(x1.w,w2v,acc[7]);
    acc[8]  = fmaf(x2.x,w2v,acc[8]);
    acc[9]  = fmaf(x2.y,w3v,acc[9]);
    acc[10] = fmaf(x2.z,w3v,acc[10]);
    acc[11] = fmaf(x2.w,w3v,acc[11]);
    acc[12] = fmaf(x3.x,w3v,acc[12]);
    acc[13] = fmaf(x3.y,w3v,acc[13]);
    acc[14] = fmaf(x3.z,w3v,acc[14]);
    acc[15] = fmaf(x3.w,w3v,acc[15]);
  }
  float4* op=(float4*)(out + (size_t)n*512 + g*16);
  op[0]=make_float4(acc[0],acc[1],acc[2],acc[3]);
  op[1]=make_float4(acc[4],acc[5],acc[6],acc[7]);
  op[2]=make_float4(acc[8],acc[9],acc[10],acc[11]);
  op[3]=make_float4(acc[12],acc[13],acc[14],acc[15]);
}

// ---------------- radial MLP hidden layers (bf16 output) ----------------
__global__ __launch_bounds__(256) void k_radial(
    const float* __restrict__ rad, const float* __restrict__ w0,
    const float* __restrict__ w1, unsigned short* __restrict__ hid, int E)
{
  __shared__ float w0s[8*64];
  __shared__ float w1s[64*64];
  int tid=threadIdx.x;
  for(int i=tid;i<512;i+=256) w0s[i]=w0[i];
  for(int i=tid;i<4096;i+=256) w1s[i]=w1[i];
  __syncthreads();
  int e=blockIdx.x*256+tid;
  if(e>=E) return;
  const float4* rp=(const float4*)(rad+(size_t)e*8);
  float4 ra=rp[0], rb=rp[1];
  float rv[8]={ra.x,ra.y,ra.z,ra.w,rb.x,rb.y,rb.z,rb.w};
  float h1[64];
  #pragma unroll 8
  for(int j=0;j<64;j++){
    float a=0.f;
    #pragma unroll
    for(int i=0;i<8;i++) a=fmaf(rv[i],w0s[i*64+j],a);
    h1[j]=a/(1.f+__expf(-a));
  }
  unsigned short* hp = hid+(size_t)e*64;
  #pragma unroll 4
  for(int j=0;j<64;j++){
    float a=0.f;
    #pragma unroll
    for(int i=0;i<64;i++) a=fmaf(h1[i],w1s[i*64+j],a);
    hp[j]=f2bf(a/(1.f+__expf(-a)));
  }
}

// ---------------- cast+transpose w2 [64 x 1088] -> w2t [1088 x 64] bf16 ----------------
__global__ __launch_bounds__(256) void k_cast_w2t(
    const float* __restrict__ w2, unsigned short* __restrict__ w2t)
{
  int t=blockIdx.x*256+threadIdx.x;
  if(t>=1088*64) return;
  int c=t>>6, k=t&63;
  w2t[(size_t)c*64+k]=f2bf(w2[(size_t)k*1088+c]);
}

// ---------------- rw GEMM via MFMA: C[rows x ncols](bf16, row-major) = A[rows x 64](bf16) * Bt^T ----------------
// Bt is [ncolsTotal x 64] bf16 (transposed weights). Layouts (HW-verified m89/m120):
//   A-frag: A[m=lane&15][k=quad*8+j];  B-frag: B[k=quad*8+j][n=lane&15];
//   D: row(M)=quad*4+reg, col(N)=lane&15.
__global__ __launch_bounds__(256) void k_gemm_mfma(
    const unsigned short* __restrict__ A, const unsigned short* __restrict__ Bt,
    unsigned short* __restrict__ C, int ldc, int ncols)
{
  int wave = threadIdx.x>>6;
  int lane = threadIdx.x&63;
  int m16 = lane&15, quad = lane>>4;
  size_t rowbase = (size_t)blockIdx.y*64;
  int col0 = blockIdx.x*128 + wave*32;
  f32x4 acc[4][2];
  #pragma unroll
  for(int mt=0;mt<4;mt++){
    #pragma unroll
    for(int nt=0;nt<2;nt++) acc[mt][nt]=(f32x4){0.f,0.f,0.f,0.f};
  }
  #pragma unroll
  for(int ks=0;ks<2;ks++){
    bf16x8 a[4], b[2];
    #pragma unroll
    for(int mt=0;mt<4;mt++)
      a[mt] = *(const bf16x8*)(A + (rowbase+mt*16+m16)*64 + ks*32 + quad*8);
    #pragma unroll
    for(int nt=0;nt<2;nt++){
      int c = col0 + nt*16 + m16;
      if (c<ncols) b[nt] = *(const bf16x8*)(Bt + (size_t)c*64 + ks*32 + quad*8);
      else         b[nt] = (bf16x8){0,0,0,0,0,0,0,0};
    }
    #pragma unroll
    for(int mt=0;mt<4;mt++){
      #pragma unroll
      for(int nt=0;nt<2;nt++)
        acc[mt][nt]=__builtin_amdgcn_mfma_f32_16x16x32_bf16(a[mt],b[nt],acc[mt][nt],0,0,0);
    }
  }
  #pragma unroll
  for(int mt=0;mt<4;mt++){
    #pragma unroll
    for(int nt=0;nt<2;nt++){
      int c = col0 + nt*16 + m16;
      if (c>=ncols) continue;
      #pragma unroll
      for(int r=0;r<4;r++){
        size_t row = rowbase + mt*16 + quad*4 + r;
        C[row*(size_t)ldc + c] = f2bf(acc[mt][nt][r]);
      }
    }
  }
}

// ---------------- edge tensor product -> per-edge messages (receiver-sorted) ----------------
// rw: [edge][col] bf16 row-major (col = p*32+f). Block = 8 edges x 32 f; rw rows
// staged via LDS (coalesced 16B global loads, then ds_read_u16 per path).
template<bool L0>
__global__ __launch_bounds__(256) void k_tp_msg(
    const float* __restrict__ hlin, const float* __restrict__ Y,
    const unsigned short* __restrict__ rw, const int* __restrict__ snd_s,
    unsigned short* __restrict__ msgs, int eb, int ecnt)
{
  constexpr int RWLD = L0 ? 128 : 1088;
  constexpr int LSTR = L0 ? 160 : 1120;   // shorts; 2*LSTR bytes = 16-bank shift between edges
  constexpr int VL = RWLD/8;
  __shared__ unsigned short rws[8*LSTR];
  int el0 = blockIdx.x*8;
  {
    int tid=threadIdx.x;
    for(int i=tid;i<8*VL;i+=256){
      int e=i/VL, v=i-e*VL;
      int elg=el0+e;
      bf16x8 val;
      if(elg<ecnt) val=*(const bf16x8*)(rw+(size_t)elg*RWLD+v*8);
      else         val=(bf16x8){0,0,0,0,0,0,0,0};
      *(bf16x8*)(&rws[e*LSTR+v*8])=val;
    }
  }
  __syncthreads();
  int le=threadIdx.x>>5, f=threadIdx.x&31;
  int el=el0+le;
  if(el>=ecnt) return;
  int j=eb+el;
  int s=snd_s[j];
  float hs[16];
  {
    const float* hp = hlin+(size_t)s*512+f*16;
    if (L0){
      hs[0]=hp[0];
      #pragma unroll
      for(int c=1;c<16;c++) hs[c]=0.f;
    } else {
      const float4* hv=(const float4*)hp;
      float4 a=hv[0],b=hv[1],cc=hv[2],d=hv[3];
      hs[0]=a.x; hs[1]=a.y; hs[2]=a.z; hs[3]=a.w;
      hs[4]=b.x; hs[5]=b.y; hs[6]=b.z; hs[7]=b.w;
      hs[8]=cc.x; hs[9]=cc.y; hs[10]=cc.z; hs[11]=cc.w;
      hs[12]=d.x; hs[13]=d.y; hs[14]=d.z; hs[15]=d.w;
    }
  }
  float yv[16];
  {
    const float4* yp=(const float4*)(Y+(size_t)j*16);
    float4 a=yp[0],b=yp[1],cc=yp[2],d=yp[3];
    yv[0]=a.x; yv[1]=a.y; yv[2]=a.z; yv[3]=a.w;
    yv[4]=b.x; yv[5]=b.y; yv[6]=b.z; yv[7]=b.w;
    yv[8]=cc.x; yv[9]=cc.y; yv[10]=cc.z; yv[11]=cc.w;
    yv[12]=d.x; yv[13]=d.y; yv[14]=d.z; yv[15]=d.w;
  }
  const unsigned short* rp = rws + le*LSTR + f;
  float acc[16];
  #pragma unroll
  for(int c=0;c<16;c++) acc[c]=0.f;
  tp_paths<L0,0>(hs,yv,rp,acc);
  bf16x8 m0, m1;
  #pragma unroll
  for(int c=0;c<8;c++){
    m0[c]=(short)f2bf(acc[c]*0.0625f);
    m1[c]=(short)f2bf(acc[8+c]*0.0625f);
  }
  bf16x8* mp=(bf16x8*)(msgs+(size_t)el*512+f*16);
  mp[0]=m0; mp[1]=m1;
}

// ---------------- CSR segment-sum of bf16 messages (no atomics) ----------------
__global__ __launch_bounds__(256) void k_seg_sum(
    const unsigned short* __restrict__ msgs, const int* __restrict__ row,
    float* __restrict__ agg, int eb, int ecnt, int N)
{
  int t=blockIdx.x*256+threadIdx.x;
  int n=t>>6, q=t&63;            // q indexes 8 consecutive floats; wave = 1 node
  if(n>=N) return;
  int lo=row[n], hi=row[n+1];
  int a0 = lo>eb ? lo : eb;
  int a1e = eb+ecnt;
  int a1 = hi<a1e ? hi : a1e;
  if(a0>=a1) return;
  float s[8];
  #pragma unroll
  for(int i=0;i<8;i++) s[i]=0.f;
  for(int j=a0;j<a1;j++){
    bf16x8 v=*(const bf16x8*)(msgs+(size_t)(j-eb)*512+q*8);
    #pragma unroll
    for(int i=0;i<8;i++) s[i]+=bf2f((unsigned short)v[i]);
  }
  float* ap=agg+(size_t)n*512+q*8;
  float4* a0p=(float4*)ap;
  float4 o0=a0p[0], o1=a0p[1];
  o0.x+=s[0]; o0.y+=s[1]; o0.z+=s[2]; o0.w+=s[3];
  o1.x+=s[4]; o1.y+=s[5]; o1.z+=s[6]; o1.w+=s[7];
  a0p[0]=o0; a0p[1]=o1;
}

// ---------------- node-wise symmetric tensor product (product basis) ----------------
__global__ __launch_bounds__(256) void k_tp_node(
    const float* __restrict__ in, float* __restrict__ out,
    const float* __restrict__ pb, const int* __restrict__ z, int N)
{
  int t=blockIdx.x*256+threadIdx.x;
  int n=t>>5, f=t&31;
  if(n>=N) return;
  float A[16];
  {
    const float4* p=(const float4*)(in+(size_t)n*512+f*16);
    float4 a=p[0],b=p[1],c=p[2],d=p[3];
    A[0]=a.x; A[1]=a.y; A[2]=a.z; A[3]=a.w;
    A[4]=b.x; A[5]=b.y; A[6]=b.z; A[7]=b.w;
    A[8]=c.x; A[9]=c.y; A[10]=c.z; A[11]=c.w;
    A[12]=d.x; A[13]=d.y; A[14]=d.z; A[15]=d.w;
  }
  float B2[16]; float B3[16];
  #pragma unroll
  for(int c=0;c<16;c++){ B2[c]=0.f; B3[c]=0.f; }
  tpn_paths<0>(A,A,B2);
  tpn_paths<0>(B2,A,B3);
  int zz=z[n];
  float wa=pb[zz*96+f], wb=pb[zz*96+32+f], wc=pb[zz*96+64+f];
  float o[16];
  #pragma unroll
  for(int c=0;c<16;c++) o[c]=wa*A[c]+wb*B2[c]+wc*B3[c];
  float4* op=(float4*)(out+(size_t)n*512+f*16);
  op[0]=make_float4(o[0],o[1],o[2],o[3]);
  op[1]=make_float4(o[4],o[5],o[6],o[7]);
  op[2]=make_float4(o[8],o[9],o[10],o[11]);
  op[3]=make_float4(o[12],o[13],o[14],o[15]);
}

// ---------------- readouts ----------------
__global__ __launch_bounds__(256) void k_resid(
    const float* __restrict__ feats, const float* __restrict__ res1,
    const int* __restrict__ z, float* __restrict__ resid, int N)
{
  int t=blockIdx.x*256+threadIdx.x;
  int n=t>>5, g=t&31;
  if(n>=N) return;
  const float* wp=res1+(size_t)z[n]*1024;
  float a=0.f;
  #pragma unroll 8
  for(int f=0;f<32;f++) a=fmaf(feats[(size_t)n*512+f*16], wp[(f<<5)+g], a);
  resid[(size_t)n*32+g]=a;
}

__global__ __launch_bounds__(256) void k_e0(
    const float* __restrict__ feats, const float* __restrict__ ro0,
    float* __restrict__ e0, int N)
{
  int n=blockIdx.x*256+threadIdx.x;
  if(n>=N) return;
  float a=0.f;
  #pragma unroll 8
  for(int f=0;f<32;f++) a=fmaf(feats[(size_t)n*512+f*16], ro0[f], a);
  e0[n]=a;
}

__global__ __launch_bounds__(256) void k_final(
    const float* __restrict__ h, const float* __restrict__ resid,
    const float* __restrict__ e0a, const float* __restrict__ ro1a,
    const float* __restrict__ ro1b, float* __restrict__ out, int N)
{
  int t=blockIdx.x*256+threadIdx.x;
  float val=0.f;
  if (t<N){
    float sc[32];
    #pragma unroll 8
    for(int f=0;f<32;f++) sc[f]=h[(size_t)t*512+f*16]+resid[(size_t)t*32+f];
    float e1=0.f;
    #pragma unroll
    for(int j=0;j<16;j++){
      float a=0.f;
      #pragma unroll
      for(int f=0;f<32;f++) a=fmaf(sc[f],ro1a[f*16+j],a);
      float s=a/(1.f+__expf(-a));
      e1=fmaf(s,ro1b[j],e1);
    }
    val = -1.5f + 2.0f*(e0a[t]+e1) - 10.0f;
  }
  __shared__ float red[256];
  red[threadIdx.x]=val;
  __syncthreads();
  for(int s=128;s>0;s>>=1){
    if(threadIdx.x<s) red[threadIdx.x]+=red[threadIdx.x+s];
    __syncthreads();
  }
  if(threadIdx.x==0) atomicAdd(out, red[0]);
}

// ---------------- host orchestration ----------------
extern "C" void kernel_launch(void* const* d_in, const int* in_sizes, int n_in,
                              void* d_out, int out_size, void* d_ws, size_t ws_size,
                              hipStream_t stream)
{
  const float* vec   =(const float*)d_in[0];
  const int*   zarr  =(const int*)  d_in[1];
  const int*   snd   =(const int*)  d_in[2];
  const int*   rcv   =(const int*)  d_in[3];
  const float* embed =(const float*)d_in[4];
  const float* r0w0  =(const float*)d_in[5];
  const float* r0w1  =(const float*)d_in[6];
  const float* r0w2  =(const float*)d_in[7];
  const float* up0   =(const float*)d_in[8];
  const float* post0 =(const float*)d_in[9];
  const float* pb0   =(const float*)d_in[10];
  const float* pblin0=(const float*)d_in[11];
  const float* r1w0  =(const float*)d_in[12];
  const float* r1w1  =(const float*)d_in[13];
  const float* r1w2  =(const float*)d_in[14];
  const float* up1   =(const float*)d_in[15];
  const float* post1 =(const float*)d_in[16];
  const float* pb1   =(const float*)d_in[17];
  const float* pblin1=(const float*)d_in[18];
  const float* sel0  =(const float*)d_in[19];
  const float* ro0   =(const float*)d_in[20];
  const float* res1  =(const float*)d_in[21];
  const float* ro1a  =(const float*)d_in[22];
  const float* ro1b  =(const float*)d_in[23];

  const int E = in_sizes[0]/3;
  const int N = in_sizes[1];
  const int Epad = (E+63)&~63;

  char* ws=(char*)d_ws;
  size_t o=0;
  auto alloc=[&](size_t bytes)->char*{
    char* p=ws+o;
    o=(o+bytes+255)&~(size_t)255;
    return p;
  };
  int*   deg  =(int*)  alloc((size_t)N*4);
  int*   rowp =(int*)  alloc((size_t)(N+1)*4);
  int*   cur  =(int*)  alloc((size_t)N*4);
  int*   eid  =(int*)  alloc((size_t)E*4);
  int*   snd_s=(int*)  alloc((size_t)E*4);
  float* Yb   =(float*)alloc((size_t)E*16*4);
  float* radb =(float*)alloc((size_t)E*8*4);
  unsigned short* hidb=(unsigned short*)alloc((size_t)Epad*64*2);
  unsigned short* w2t0=(unsigned short*)alloc((size_t)1088*64*2);
  unsigned short* w2t1=(unsigned short*)alloc((size_t)1088*64*2);
  float* feats=(float*)alloc((size_t)N*512*4);
  float* bufA =(float*)alloc((size_t)N*512*4);
  float* bufB =(float*)alloc((size_t)N*512*4);
  float* bufC =(float*)alloc((size_t)N*512*4);
  float* e0b  =(float*)alloc((size_t)N*4);
  float* residb=(float*)alloc((size_t)N*32*4);
  char*  dyn  = ws+o;
  size_t remain = ws_size>o ? ws_size-o : 0;

  dim3 tb(256);
  dim3 nblk((unsigned)((N*32+255)/256));
  dim3 eblk((unsigned)((E+255)/256));
  dim3 qblk((unsigned)((N*64+255)/256));

  // CSR build (receiver-sorted edge order)
  hipMemsetAsync(deg,0,(size_t)N*4,stream);
  k_count<<<eblk,tb,0,stream>>>(rcv,deg,E);
  k_scan<<<dim3(1),dim3(1024),0,stream>>>(deg,rowp,cur,N);
  k_fill<<<eblk,tb,0,stream>>>(rcv,cur,eid,E);

  k_edge_setup<<<eblk,tb,0,stream>>>(vec,snd,eid,Yb,radb,snd_s,E);
  k_node_init<<<nblk,tb,0,stream>>>(embed,zarr,feats,N);

  // cast+transpose radial-MLP final weights to bf16 (per launch)
  k_cast_w2t<<<dim3((1088*64+255)/256),tb,0,stream>>>(r0w2,w2t0);
  k_cast_w2t<<<dim3((1088*64+255)/256),tb,0,stream>>>(r1w2,w2t1);

  auto run_edges=[&](bool l0, const float* hlin, const unsigned short* w2t, float* agg){
    const int rwld = l0?128:1088;
    size_t per = (size_t)rwld*2 + 1024;      // rw(bf16, row-major) + msgs(bf16) per edge
    long rows = (long)(remain/per);
    rows -= rows%64;
    if (rows>(long)Epad) rows=Epad;
    if (rows<64) rows=64;
    unsigned short* rwb = (unsigned short*)dyn;
    unsigned short* msgsb = (unsigned short*)(dyn + (((size_t)rows*(size_t)rwld*2 + 255)&~(size_t)255));
    for(long eb=0;eb<E;eb+=rows){
      long cnt = E-eb; if(cnt>rows) cnt=rows;
      long cntp = (cnt+63)&~63L;
      dim3 g((unsigned)((rwld+127)/128),(unsigned)(cntp/64));
      k_gemm_mfma<<<g,tb,0,stream>>>(hidb+(size_t)eb*64, w2t, rwb, rwld, rwld);
      dim3 g2((unsigned)((cnt+7)/8));
      if(l0) k_tp_msg<true ><<<g2,tb,0,stream>>>(hlin,Yb,rwb,snd_s,msgsb,(int)eb,(int)cnt);
      else   k_tp_msg<false><<<g2,tb,0,stream>>>(hlin,Yb,rwb,snd_s,msgsb,(int)eb,(int)cnt);
      k_seg_sum<<<qblk,tb,0,stream>>>(msgsb,rowp,agg,(int)eb,(int)cnt,N);
    }
  };

  // ---- layer 0 ----
  k_lin<<<nblk,tb,0,stream>>>(feats,bufA,up0,(const int*)nullptr,0,N);
  k_radial<<<eblk,tb,0,stream>>>(radb,r0w0,r0w1,hidb,E);
  hipMemsetAsync(bufB,0,(size_t)N*512*4,stream);
  run_edges(true,bufA,w2t0,bufB);
  k_lin<<<nblk,tb,0,stream>>>(bufB,bufC,post0,(const int*)nullptr,0,N);
  k_lin<<<nblk,tb,0,stream>>>(bufC,bufA,sel0,zarr,4096,N);
  k_tp_node<<<nblk,tb,0,stream>>>(bufA,bufB,pb0,zarr,N);
  k_lin<<<nblk,tb,0,stream>>>(bufB,feats,pblin0,(const int*)nullptr,0,N);
  k_e0<<<dim3((N+255)/256),tb,0,stream>>>(feats,ro0,e0b,N);
  k_resid<<<nblk,tb,0,stream>>>(feats,res1,zarr,residb,N);

  // ---- layer 1 ----
  k_lin<<<nblk,tb,0,stream>>>(feats,bufA,up1,(const int*)nullptr,0,N);
  k_radial<<<eblk,tb,0,stream>>>(radb,r1w0,r1w1,hidb,E);
  hipMemsetAsync(bufC,0,(size_t)N*512*4,stream);
  run_edges(false,bufA,w2t1,bufC);
  k_lin<<<nblk,tb,0,stream>>>(bufC,bufB,post1,(const int*)nullptr,0,N);
  k_tp_node<<<nblk,tb,0,stream>>>(bufB,bufA,pb1,zarr,N);
  k_lin<<<nblk,tb,0,stream>>>(bufA,bufC,pblin1,(const int*)nullptr,0,N);

  hipMemsetAsync(d_out,0,4,stream);
  k_final<<<dim3((N+255)/256),tb,0,stream>>>(bufC,residb,e0b,ro1a,ro1b,(float*)d_out,N);
}

// Round 9
// 1050.689 us; speedup vs baseline: 2.8415x; 1.1551x over previous
//
#include <hip/hip_runtime.h>
#include <math.h>

// ---------------- static config ----------------
#define NF 32
#define NPATHS 34

typedef __attribute__((ext_vector_type(8))) short bf16x8;
typedef __attribute__((ext_vector_type(4))) float f32x4;

__device__ __forceinline__ unsigned short f2bf(float v){
  unsigned u = __float_as_uint(v);
  u += 0x7fffu + ((u>>16)&1u);
  return (unsigned short)(u>>16);
}
__device__ __forceinline__ float bf2f(unsigned short h){
  return __uint_as_float(((unsigned)h)<<16);
}

struct PathTab { int l1[NPATHS]; int l2[NPATHS]; int l3[NPATHS]; };
constexpr PathTab mkpaths(){
  PathTab t{}; int n=0;
  for(int a=0;a<=3;a++)for(int b=0;b<=3;b++)for(int c=0;c<=3;c++){
    int lo = a>b ? a-b : b-a;
    if(c>=lo && c<=a+b){ t.l1[n]=a; t.l2[n]=b; t.l3[n]=c; n++; }
  }
  return t;
}
constexpr PathTab PT = mkpaths();

// ---------------- compile-time Wigner-3j (exact replica of reference math) ----------------
struct FactT { double v[22]; };
constexpr FactT mkfactT(){ FactT f{}; f.v[0]=1.0; for(int i=1;i<22;i++) f.v[i]=f.v[i-1]*(double)i; return f; }
constexpr FactT FT = mkfactT();
constexpr double cfact(int n){ return FT.v[n]; }

constexpr double csqrt(double x){
  if(x<=0.0) return 0.0;
  double g = x<1.0 ? 1.0 : x;
  for(int i=0;i<40;i++) g=0.5*(g+x/g);
  return g;
}

constexpr double su2cg(int j1,int j2,int j3,int m1,int m2){
  int m3=m1+m2;
  if(m3<-j3||m3>j3) return 0.0;
  double pref = (double)(2*j3+1)*cfact(j3+j1-j2)*cfact(j3-j1+j2)*cfact(j1+j2-j3)/cfact(j1+j2+j3+1);
  pref *= cfact(j3+m3)*cfact(j3-m3)*cfact(j1-m1)*cfact(j1+m1)*cfact(j2-m2)*cfact(j2+m2);
  pref = csqrt(pref);
  int k0=0; if(j2-j3-m1>k0)k0=j2-j3-m1; if(j1-j3+m2>k0)k0=j1-j3+m2;
  int k1=j1+j2-j3; if(j1-m1<k1)k1=j1-m1; if(j2+m2<k1)k1=j2+m2;
  double s=0.0;
  for(int k=k0;k<=k1;k++){
    double d = cfact(k)*cfact(j1+j2-j3-k)*cfact(j1-m1-k)*cfact(j2+m2-k)*cfact(j3-j2+m1+k)*cfact(j3-j1-m2+k);
    s += (k&1)? -1.0/d : 1.0/d;
  }
  return pref*s;
}

struct ccd { double x, y; };
constexpr ccd cqval(int l,int r,int col){
  const double is2 = 0.70710678118654752440;
  double re=0.0, im=0.0;
  if (r<l){ if (col==2*l-r) re=is2; else if (col==r) im=-is2; }
  else if (r==l){ if (col==l) re=1.0; }
  else { double s = ((r-l)&1)? -1.0:1.0;
         if (col==r) re=s*is2; else if (col==2*l-r) im=s*is2; }
  ccd v{re,im};
  switch(l&3){           // multiply by (-i)^l
    case 1: return ccd{ v.y, -v.x };
    case 2: return ccd{-v.x, -v.y };
    case 3: return ccd{-v.y,  v.x };
    default: return v;
  }
}

constexpr double w3entry(int l1,int l2,int l3,int i,int j,int k){
  double re=0.0;
  for(int a=0;a<2*l1+1;a++){
    ccd qa=cqval(l1,a,i); if(qa.x==0.0&&qa.y==0.0) continue;
    for(int b=0;b<2*l2+1;b++){
      ccd qb=cqval(l2,b,j); if(qb.x==0.0&&qb.y==0.0) continue;
      int m1=a-l1, m2=b-l2, m3=m1+m2;
      if(m3<-l3||m3>l3) continue;
      int c=m3+l3;
      double cg=su2cg(l1,l2,l3,m1,m2); if(cg==0.0) continue;
      ccd qc=cqval(l3,c,k); qc.y=-qc.y;   // conj
      if(qc.x==0.0&&qc.y==0.0) continue;
      ccd ab{qa.x*qb.x-qa.y*qb.y, qa.x*qb.y+qa.y*qb.x};
      re += cg*(ab.x*qc.x - ab.y*qc.y);
    }
  }
  return re;
}

template<int L1,int L2,int L3> struct W3Arr { float v[(2*L1+1)*(2*L2+1)*(2*L3+1)]; };
template<int L1,int L2,int L3> constexpr W3Arr<L1,L2,L3> mkW3(double scale){
  W3Arr<L1,L2,L3> r{};
  for(int i=0;i<2*L1+1;i++)
    for(int j=0;j<2*L2+1;j++)
      for(int k=0;k<2*L3+1;k++)
        r.v[(i*(2*L2+1)+j)*(2*L3+1)+k] = (float)(w3entry(L1,L2,L3,i,j,k)*scale);
  return r;
}
template<int L1,int L2,int L3> constexpr W3Arr<L1,L2,L3> W3V = mkW3<L1,L2,L3>(1.0);
template<int L1,int L2,int L3> constexpr W3Arr<L1,L2,L3> W3N = mkW3<L1,L2,L3>(1.0/csqrt(2.0*L3+1.0));

// SH recursion scales (replica of reference _sh_scales, float64 like numpy)
struct SCt { double sc2, sc3; };
constexpr SCt mksc(){
  double v0=0.2,v1=-0.6,v2=0.7;
  double nv=csqrt(v0*v0+v1*v1+v2*v2);
  double s3=csqrt(3.0);
  double y1[3]={s3*v0/nv, s3*v1/nv, s3*v2/nv};
  double t2[5]={0,0,0,0,0}; double n2=0.0;
  for(int c=0;c<5;c++){
    double s=0.0;
    for(int a=0;a<3;a++)for(int b=0;b<3;b++) s += w3entry(1,1,2,a,b,c)*y1[a]*y1[b];
    t2[c]=s; n2+=s*s;
  }
  double sc2=csqrt(5.0)/csqrt(n2);
  double y2[5]={sc2*t2[0],sc2*t2[1],sc2*t2[2],sc2*t2[3],sc2*t2[4]};
  double n3=0.0;
  for(int c=0;c<7;c++){
    double s=0.0;
    for(int a=0;a<5;a++)for(int b=0;b<3;b++) s += w3entry(2,1,3,a,b,c)*y2[a]*y1[b];
    n3+=s*s;
  }
  double sc3=csqrt(7.0)/csqrt(n3);
  return SCt{sc2,sc3};
}
constexpr SCt SCV = mksc();

// ---------------- template-unrolled TP with literal W3J, true-zero elision ----------------
template<bool NORM,int l1,int l2,int l3,int A,int B,int C>
__device__ __forceinline__ void w3term(const float* __restrict__ x, const float* __restrict__ y,
                                       float rv, float* __restrict__ acc){
  constexpr float w = NORM ? W3N<l1,l2,l3>.v[(A*(2*l2+1)+B)*(2*l3+1)+C]
                           : W3V<l1,l2,l3>.v[(A*(2*l2+1)+B)*(2*l3+1)+C];
  if constexpr (w!=0.0f)
    acc[l3*l3+C] = fmaf(w, x[l1*l1+A]*y[l2*l2+B]*rv, acc[l3*l3+C]);
}
template<bool NORM,int l1,int l2,int l3,int A,int B,int C>
__device__ __forceinline__ void w3loopC(const float* x,const float* y,float rv,float* acc){
  if constexpr (C<2*l3+1){
    w3term<NORM,l1,l2,l3,A,B,C>(x,y,rv,acc);
    w3loopC<NORM,l1,l2,l3,A,B,C+1>(x,y,rv,acc);
  }
}
template<bool NORM,int l1,int l2,int l3,int A,int B>
__device__ __forceinline__ void w3loopB(const float* x,const float* y,float rv,float* acc){
  if constexpr (B<2*l2+1){
    w3loopC<NORM,l1,l2,l3,A,B,0>(x,y,rv,acc);
    w3loopB<NORM,l1,l2,l3,A,B+1>(x,y,rv,acc);
  }
}
template<bool NORM,int l1,int l2,int l3,int A>
__device__ __forceinline__ void w3loopA(const float* x,const float* y,float rv,float* acc){
  if constexpr (A<2*l1+1){
    w3loopB<NORM,l1,l2,l3,A,0>(x,y,rv,acc);
    w3loopA<NORM,l1,l2,l3,A+1>(x,y,rv,acc);
  }
}

template<bool L0,int P>
__device__ __forceinline__ void tp_paths(const float* hs,const float* yv,
                                         const unsigned short* rp, float* acc){
  if constexpr (P<NPATHS){
    constexpr int l1=PT.l1[P], l2=PT.l2[P], l3=PT.l3[P];
    if constexpr (!(L0 && l1!=0)){
      float rv = bf2f(rp[P*32]);
      w3loopA<false,l1,l2,l3,0>(hs,yv,rv,acc);
    }
    tp_paths<L0,P+1>(hs,yv,rp,acc);
  }
}

template<int P>
__device__ __forceinline__ void tpn_paths(const float* x,const float* y,float* o){
  if constexpr (P<NPATHS){
    constexpr int l1=PT.l1[P], l2=PT.l2[P], l3=PT.l3[P];
    w3loopA<true,l1,l2,l3,0>(x,y,1.0f,o);
    tpn_paths<P+1>(x,y,o);
  }
}

// ---------------- CSR build: degree count, scan, fill ----------------
__global__ __launch_bounds__(256) void k_count(
    const int* __restrict__ rcv, int* __restrict__ deg, int E)
{
  int e=blockIdx.x*256+threadIdx.x;
  if(e>=E) return;
  atomicAdd(&deg[rcv[e]],1);
}

#define SCAN_PER 32
__global__ __launch_bounds__(1024) void k_scan(
    const int* __restrict__ deg, int* __restrict__ row,
    int* __restrict__ cur, int N)
{
  __shared__ int part[1024];
  int t=threadIdx.x;
  int per=(N+1023)/1024; if(per>SCAN_PER) per=SCAN_PER;
  int base=t*per;
  int loc[SCAN_PER];
  int s=0;
  for(int i=0;i<per;i++){ int idx=base+i; int v=(idx<N)? deg[idx]:0; loc[i]=s; s+=v; }
  part[t]=s;
  __syncthreads();
  for(int off=1;off<1024;off<<=1){
    int v=(t>=off)? part[t-off]:0;
    __syncthreads();
    part[t]+=v;
    __syncthreads();
  }
  int ex=(t==0)?0:part[t-1];
  for(int i=0;i<per;i++){
    int idx=base+i;
    if(idx<N){ int r=ex+loc[i]; row[idx]=r; cur[idx]=r; }
  }
  if(t==1023) row[N]=part[1023];
}

__global__ __launch_bounds__(256) void k_fill(
    const int* __restrict__ rcv, int* __restrict__ cur,
    int* __restrict__ eid, int E)
{
  int e=blockIdx.x*256+threadIdx.x;
  if(e>=E) return;
  int pos=atomicAdd(&cur[rcv[e]],1);
  eid[pos]=e;
}

// ---------------- per-edge geometry (receiver-sorted order): SH + radial basis ----------------
__global__ __launch_bounds__(256) void k_edge_setup(
    const float* __restrict__ vec, const int* __restrict__ snd,
    const int* __restrict__ eid, float* __restrict__ Y,
    float* __restrict__ rad, int* __restrict__ snd_s, int E)
{
  int j = blockIdx.x*256+threadIdx.x;
  if (j>=E) return;
  int e = eid[j];
  snd_s[j]=snd[e];
  float vx=vec[3*e], vy=vec[3*e+1], vz=vec[3*e+2];
  float r=sqrtf(vx*vx+vy*vy+vz*vz);
  float inv=1.0f/fmaxf(r,1e-9f);
  float y[16];
  y[0]=1.0f;
  const float s3=1.7320508075688772f;
  y[1]=s3*vx*inv; y[2]=s3*vy*inv; y[3]=s3*vz*inv;
  constexpr float sc2=(float)SCV.sc2, sc3=(float)SCV.sc3;
  {
    float t[16];
    #pragma unroll
    for(int c=0;c<16;c++) t[c]=0.f;
    w3loopA<false,1,1,2,0>(y,y,1.0f,t);     // t[4..8] = einsum(w112, y1, y1)
    #pragma unroll
    for(int c=0;c<5;c++) y[4+c]=sc2*t[4+c];
    w3loopA<false,2,1,3,0>(y,y,1.0f,t);     // t[9..15] = einsum(w213, y2, y1)
    #pragma unroll
    for(int c=0;c<7;c++) y[9+c]=sc3*t[9+c];
  }
  float4* Yp=(float4*)(Y+(size_t)j*16);
  Yp[0]=make_float4(y[0],y[1],y[2],y[3]);
  Yp[1]=make_float4(y[4],y[5],y[6],y[7]);
  Yp[2]=make_float4(y[8],y[9],y[10],y[11]);
  Yp[3]=make_float4(y[12],y[13],y[14],y[15]);
  float x = r*0.2f;
  float env=0.f;
  if (x<1.0f){
    float x2=x*x; float x4=x2*x2; float x5=x4*x;
    env = 1.0f - 21.0f*x5 + 35.0f*x5*x - 15.0f*x5*x2;
  }
  const float cb = 0.632455532033675866f; // sqrt(2/5)
  float base = inv*env*cb;
  #pragma unroll
  for(int n=1;n<=8;n++)
    rad[(size_t)j*8 + n-1] = base*sinf(3.14159265358979323846f * x * (float)n);
}

// ---------------- node init: scalar embedding ----------------
__global__ __launch_bounds__(256) void k_node_init(
    const float* __restrict__ embed, const int* __restrict__ z,
    float* __restrict__ feats, int N)
{
  int t = blockIdx.x*256+threadIdx.x;
  int n=t>>5, f=t&31;
  if(n>=N) return;
  float v = embed[z[n]*NF + f];
  float4* p=(float4*)(feats + (size_t)n*512 + f*16);
  p[0]=make_float4(v,0.f,0.f,0.f);
  p[1]=make_float4(0.f,0.f,0.f,0.f);
  p[2]=make_float4(0.f,0.f,0.f,0.f);
  p[3]=make_float4(0.f,0.f,0.f,0.f);
}

// ---------------- per-l channel-mixing linear (optionally per-species weights) ----------------
__global__ __launch_bounds__(256) void k_lin(
    const float* __restrict__ in, float* __restrict__ out,
    const float* __restrict__ w, const int* __restrict__ z, int zstride, int N)
{
  int t=blockIdx.x*256+threadIdx.x;
  int n=t>>5, g=t&31;
  if(n>=N) return;
  const float* wp = w + (z ? (size_t)z[n]*(size_t)zstride : 0);
  const float* ip = in + (size_t)n*512;
  float acc[16];
  #pragma unroll
  for(int c=0;c<16;c++) acc[c]=0.f;
  #pragma unroll 8
  for(int f=0; f<NF; f++){
    const float4* xp = (const float4*)(ip + f*16);
    float4 x0=xp[0], x1=xp[1], x2=xp[2], x3=xp[3];
    float w0v=wp[(f<<5)+g], w1v=wp[1024+(f<<5)+g], w2v=wp[2048+(f<<5)+g], w3v=wp[3072+(f<<5)+g];
    acc[0]  = fmaf(x0.x,w0v,acc[0]);
    acc[1]  = fmaf(x0.y,w1v,acc[1]);
    acc[2]  = fmaf(x0.z,w1v,acc[2]);
    acc[3]  = fmaf(x0.w,w1v,acc[3]);
    acc[4]  = fmaf(x1.x,w2v,acc[4]);
    acc[5]  = fmaf(x1.y,w2v,acc[5]);
    acc[6]  = fmaf(x1.z,w2v,acc[6]);
    acc[7]  = fmaf(x1.w,w2v,acc[7]);
    acc[8]  = fmaf(x2.x,w2v,acc[8]);
    acc[9]  = fmaf(x2.y,w3v,acc[9]);
    acc[10] = fmaf(x2.z,w3v,acc[10]);
    acc[11] = fmaf(x2.w,w3v,acc[11]);
    acc[12] = fmaf(x3.x,w3v,acc[12]);
    acc[13] = fmaf(x3.y,w3v,acc[13]);
    acc[14] = fmaf(x3.z,w3v,acc[14]);
    acc[15] = fmaf(x3.w,w3v,acc[15]);
  }
  float4* op=(float4*)(out + (size_t)n*512 + g*16);
  op[0]=make_float4(acc[0],acc[1],acc[2],acc[3]);
  op[1]=make_float4(acc[4],acc[5],acc[6],acc[7]);
  op[2]=make_float4(acc[8],acc[9],acc[10],acc[11]);
  op[3]=make_float4(acc[12],acc[13],acc[14],acc[15]);
}

// ---------------- radial MLP hidden layers (bf16 output) ----------------
__global__ __launch_bounds__(256) void k_radial(
    const float* __restrict__ rad, const float* __restrict__ w0,
    const float* __restrict__ w1, unsigned short* __restrict__ hid, int E)
{
  __shared__ float w0s[8*64];
  __shared__ float w1s[64*64];
  int tid=threadIdx.x;
  for(int i=tid;i<512;i+=256) w0s[i]=w0[i];
  for(int i=tid;i<4096;i+=256) w1s[i]=w1[i];
  __syncthreads();
  int e=blockIdx.x*256+tid;
  if(e>=E) return;
  const float4* rp=(const float4*)(rad+(size_t)e*8);
  float4 ra=rp[0], rb=rp[1];
  float rv[8]={ra.x,ra.y,ra.z,ra.w,rb.x,rb.y,rb.z,rb.w};
  float h1[64];
  #pragma unroll 8
  for(int j=0;j<64;j++){
    float a=0.f;
    #pragma unroll
    for(int i=0;i<8;i++) a=fmaf(rv[i],w0s[i*64+j],a);
    h1[j]=a/(1.f+__expf(-a));
  }
  unsigned short* hp = hid+(size_t)e*64;
  #pragma unroll 4
  for(int j=0;j<64;j++){
    float a=0.f;
    #pragma unroll
    for(int i=0;i<64;i++) a=fmaf(h1[i],w1s[i*64+j],a);
    hp[j]=f2bf(a/(1.f+__expf(-a)));
  }
}

// ---------------- cast+transpose w2 [64 x 1088] -> w2t [1088 x 64] bf16 ----------------
__global__ __launch_bounds__(256) void k_cast_w2t(
    const float* __restrict__ w2, unsigned short* __restrict__ w2t)
{
  int t=blockIdx.x*256+threadIdx.x;
  if(t>=1088*64) return;
  int c=t>>6, k=t&63;
  w2t[(size_t)c*64+k]=f2bf(w2[(size_t)k*1088+c]);
}

// ---------------- FUSED: MFMA rw-GEMM (to LDS) + edge tensor product -> messages ----------------
// Block = 16 edges. Phase 1: rw[16 x RWLD] = hid[16x64] @ w2t^T via 16x16x32 MFMA,
// D written straight to LDS in [edge][col] layout (col = p*32+f), LSTR padded.
// Phase 2: constexpr-W3J TP per (edge,f), 2 edges per thread.
// MFMA layouts (HW-verified m89/m120): A-frag A[m=lane&15][k=quad*8+j];
// B-frag B[k=quad*8+j][n=lane&15]; D: row=quad*4+reg, col=lane&15.
template<bool L0>
__global__ __launch_bounds__(256) void k_tp_fused(
    const float* __restrict__ hlin, const float* __restrict__ Y,
    const unsigned short* __restrict__ hid, const unsigned short* __restrict__ w2t,
    const int* __restrict__ snd_s, unsigned short* __restrict__ msgs,
    int eb, int ecnt)
{
  constexpr int RWLD = L0 ? 128 : 1088;
  constexpr int LSTR = L0 ? 160 : 1120;   // shorts; 2*LSTR bytes = 16-bank shift between edges
  __shared__ unsigned short rws[16*LSTR];
  int tid=threadIdx.x;
  int lane=tid&63, wave=tid>>6;
  int m16=lane&15, quad=lane>>4;
  int el0=blockIdx.x*16;
  // ---- phase 1: rw tile via MFMA, D -> LDS ----
  {
    const unsigned short* Ab = hid + (size_t)el0*64;   // hid already offset by eb
    bf16x8 a0 = *(const bf16x8*)(Ab + m16*64 + quad*8);
    bf16x8 a1 = *(const bf16x8*)(Ab + m16*64 + 32 + quad*8);
    #pragma unroll 2
    for(int nt=wave; nt<RWLD/16; nt+=4){
      int col = nt*16 + m16;
      bf16x8 b0 = *(const bf16x8*)(w2t + (size_t)col*64 + quad*8);
      bf16x8 b1 = *(const bf16x8*)(w2t + (size_t)col*64 + 32 + quad*8);
      f32x4 acc = (f32x4){0.f,0.f,0.f,0.f};
      acc = __builtin_amdgcn_mfma_f32_16x16x32_bf16(a0,b0,acc,0,0,0);
      acc = __builtin_amdgcn_mfma_f32_16x16x32_bf16(a1,b1,acc,0,0,0);
      #pragma unroll
      for(int r=0;r<4;r++)
        rws[(quad*4+r)*LSTR + col] = f2bf(acc[r]);
    }
  }
  __syncthreads();
  // ---- phase 2: TP per (edge,f), 2 sub-rounds of 8 edges ----
  int f=tid&31;
  #pragma unroll
  for(int sub=0;sub<2;sub++){
    int le=(tid>>5)+sub*8;
    int el=el0+le;
    if(el>=ecnt) continue;
    int j=eb+el;
    int s=snd_s[j];
    float hs[16];
    {
      const float* hp = hlin+(size_t)s*512+f*16;
      if (L0){
        hs[0]=hp[0];
        #pragma unroll
        for(int c=1;c<16;c++) hs[c]=0.f;
      } else {
        const float4* hv=(const float4*)hp;
        float4 a=hv[0],b=hv[1],cc=hv[2],d=hv[3];
        hs[0]=a.x; hs[1]=a.y; hs[2]=a.z; hs[3]=a.w;
        hs[4]=b.x; hs[5]=b.y; hs[6]=b.z; hs[7]=b.w;
        hs[8]=cc.x; hs[9]=cc.y; hs[10]=cc.z; hs[11]=cc.w;
        hs[12]=d.x; hs[13]=d.y; hs[14]=d.z; hs[15]=d.w;
      }
    }
    float yv[16];
    {
      const float4* yp=(const float4*)(Y+(size_t)j*16);
      float4 a=yp[0],b=yp[1],cc=yp[2],d=yp[3];
      yv[0]=a.x; yv[1]=a.y; yv[2]=a.z; yv[3]=a.w;
      yv[4]=b.x; yv[5]=b.y; yv[6]=b.z; yv[7]=b.w;
      yv[8]=cc.x; yv[9]=cc.y; yv[10]=cc.z; yv[11]=cc.w;
      yv[12]=d.x; yv[13]=d.y; yv[14]=d.z; yv[15]=d.w;
    }
    const unsigned short* rp = rws + le*LSTR + f;
    float acc[16];
    #pragma unroll
    for(int c=0;c<16;c++) acc[c]=0.f;
    tp_paths<L0,0>(hs,yv,rp,acc);
    bf16x8 m0, m1;
    #pragma unroll
    for(int c=0;c<8;c++){
      m0[c]=(short)f2bf(acc[c]*0.0625f);
      m1[c]=(short)f2bf(acc[8+c]*0.0625f);
    }
    bf16x8* mp=(bf16x8*)(msgs+(size_t)el*512+f*16);
    mp[0]=m0; mp[1]=m1;
  }
}

// ---------------- CSR segment-sum of bf16 messages (no atomics) ----------------
__global__ __launch_bounds__(256) void k_seg_sum(
    const unsigned short* __restrict__ msgs, const int* __restrict__ row,
    float* __restrict__ agg, int eb, int ecnt, int N)
{
  int t=blockIdx.x*256+threadIdx.x;
  int n=t>>6, q=t&63;            // q indexes 8 consecutive floats; wave = 1 node
  if(n>=N) return;
  int lo=row[n], hi=row[n+1];
  int a0 = lo>eb ? lo : eb;
  int a1e = eb+ecnt;
  int a1 = hi<a1e ? hi : a1e;
  if(a0>=a1) return;
  float s[8];
  #pragma unroll
  for(int i=0;i<8;i++) s[i]=0.f;
  for(int j=a0;j<a1;j++){
    bf16x8 v=*(const bf16x8*)(msgs+(size_t)(j-eb)*512+q*8);
    #pragma unroll
    for(int i=0;i<8;i++) s[i]+=bf2f((unsigned short)v[i]);
  }
  float* ap=agg+(size_t)n*512+q*8;
  float4* a0p=(float4*)ap;
  float4 o0=a0p[0], o1=a0p[1];
  o0.x+=s[0]; o0.y+=s[1]; o0.z+=s[2]; o0.w+=s[3];
  o1.x+=s[4]; o1.y+=s[5]; o1.z+=s[6]; o1.w+=s[7];
  a0p[0]=o0; a0p[1]=o1;
}

// ---------------- node-wise symmetric tensor product (product basis) ----------------
__global__ __launch_bounds__(256) void k_tp_node(
    const float* __restrict__ in, float* __restrict__ out,
    const float* __restrict__ pb, const int* __restrict__ z, int N)
{
  int t=blockIdx.x*256+threadIdx.x;
  int n=t>>5, f=t&31;
  if(n>=N) return;
  float A[16];
  {
    const float4* p=(const float4*)(in+(size_t)n*512+f*16);
    float4 a=p[0],b=p[1],c=p[2],d=p[3];
    A[0]=a.x; A[1]=a.y; A[2]=a.z; A[3]=a.w;
    A[4]=b.x; A[5]=b.y; A[6]=b.z; A[7]=b.w;
    A[8]=c.x; A[9]=c.y; A[10]=c.z; A[11]=c.w;
    A[12]=d.x; A[13]=d.y; A[14]=d.z; A[15]=d.w;
  }
  float B2[16]; float B3[16];
  #pragma unroll
  for(int c=0;c<16;c++){ B2[c]=0.f; B3[c]=0.f; }
  tpn_paths<0>(A,A,B2);
  tpn_paths<0>(B2,A,B3);
  int zz=z[n];
  float wa=pb[zz*96+f], wb=pb[zz*96+32+f], wc=pb[zz*96+64+f];
  float o[16];
  #pragma unroll
  for(int c=0;c<16;c++) o[c]=wa*A[c]+wb*B2[c]+wc*B3[c];
  float4* op=(float4*)(out+(size_t)n*512+f*16);
  op[0]=make_float4(o[0],o[1],o[2],o[3]);
  op[1]=make_float4(o[4],o[5],o[6],o[7]);
  op[2]=make_float4(o[8],o[9],o[10],o[11]);
  op[3]=make_float4(o[12],o[13],o[14],o[15]);
}

// ---------------- readouts ----------------
__global__ __launch_bounds__(256) void k_resid(
    const float* __restrict__ feats, const float* __restrict__ res1,
    const int* __restrict__ z, float* __restrict__ resid, int N)
{
  int t=blockIdx.x*256+threadIdx.x;
  int n=t>>5, g=t&31;
  if(n>=N) return;
  const float* wp=res1+(size_t)z[n]*1024;
  float a=0.f;
  #pragma unroll 8
  for(int f=0;f<32;f++) a=fmaf(feats[(size_t)n*512+f*16], wp[(f<<5)+g], a);
  resid[(size_t)n*32+g]=a;
}

__global__ __launch_bounds__(256) void k_e0(
    const float* __restrict__ feats, const float* __restrict__ ro0,
    float* __restrict__ e0, int N)
{
  int n=blockIdx.x*256+threadIdx.x;
  if(n>=N) return;
  float a=0.f;
  #pragma unroll 8
  for(int f=0;f<32;f++) a=fmaf(feats[(size_t)n*512+f*16], ro0[f], a);
  e0[n]=a;
}

__global__ __launch_bounds__(256) void k_final(
    const float* __restrict__ h, const float* __restrict__ resid,
    const float* __restrict__ e0a, const float* __restrict__ ro1a,
    const float* __restrict__ ro1b, float* __restrict__ out, int N)
{
  int t=blockIdx.x*256+threadIdx.x;
  float val=0.f;
  if (t<N){
    float sc[32];
    #pragma unroll 8
    for(int f=0;f<32;f++) sc[f]=h[(size_t)t*512+f*16]+resid[(size_t)t*32+f];
    float e1=0.f;
    #pragma unroll
    for(int j=0;j<16;j++){
      float a=0.f;
      #pragma unroll
      for(int f=0;f<32;f++) a=fmaf(sc[f],ro1a[f*16+j],a);
      float s=a/(1.f+__expf(-a));
      e1=fmaf(s,ro1b[j],e1);
    }
    val = -1.5f + 2.0f*(e0a[t]+e1) - 10.0f;
  }
  __shared__ float red[256];
  red[threadIdx.x]=val;
  __syncthreads();
  for(int s=128;s>0;s>>=1){
    if(threadIdx.x<s) red[threadIdx.x]+=red[threadIdx.x+s];
    __syncthreads();
  }
  if(threadIdx.x==0) atomicAdd(out, red[0]);
}

// ---------------- host orchestration ----------------
extern "C" void kernel_launch(void* const* d_in, const int* in_sizes, int n_in,
                              void* d_out, int out_size, void* d_ws, size_t ws_size,
                              hipStream_t stream)
{
  const float* vec   =(const float*)d_in[0];
  const int*   zarr  =(const int*)  d_in[1];
  const int*   snd   =(const int*)  d_in[2];
  const int*   rcv   =(const int*)  d_in[3];
  const float* embed =(const float*)d_in[4];
  const float* r0w0  =(const float*)d_in[5];
  const float* r0w1  =(const float*)d_in[6];
  const float* r0w2  =(const float*)d_in[7];
  const float* up0   =(const float*)d_in[8];
  const float* post0 =(const float*)d_in[9];
  const float* pb0   =(const float*)d_in[10];
  const float* pblin0=(const float*)d_in[11];
  const float* r1w0  =(const float*)d_in[12];
  const float* r1w1  =(const float*)d_in[13];
  const float* r1w2  =(const float*)d_in[14];
  const float* up1   =(const float*)d_in[15];
  const float* post1 =(const float*)d_in[16];
  const float* pb1   =(const float*)d_in[17];
  const float* pblin1=(const float*)d_in[18];
  const float* sel0  =(const float*)d_in[19];
  const float* ro0   =(const float*)d_in[20];
  const float* res1  =(const float*)d_in[21];
  const float* ro1a  =(const float*)d_in[22];
  const float* ro1b  =(const float*)d_in[23];

  const int E = in_sizes[0]/3;
  const int N = in_sizes[1];
  const int Epad = (E+63)&~63;

  char* ws=(char*)d_ws;
  size_t o=0;
  auto alloc=[&](size_t bytes)->char*{
    char* p=ws+o;
    o=(o+bytes+255)&~(size_t)255;
    return p;
  };
  int*   deg  =(int*)  alloc((size_t)N*4);
  int*   rowp =(int*)  alloc((size_t)(N+1)*4);
  int*   cur  =(int*)  alloc((size_t)N*4);
  int*   eid  =(int*)  alloc((size_t)E*4);
  int*   snd_s=(int*)  alloc((size_t)E*4);
  float* Yb   =(float*)alloc((size_t)E*16*4);
  float* radb =(float*)alloc((size_t)E*8*4);
  unsigned short* hidb=(unsigned short*)alloc((size_t)Epad*64*2);
  unsigned short* w2t0=(unsigned short*)alloc((size_t)1088*64*2);
  unsigned short* w2t1=(unsigned short*)alloc((size_t)1088*64*2);
  float* feats=(float*)alloc((size_t)N*512*4);
  float* bufA =(float*)alloc((size_t)N*512*4);
  float* bufB =(float*)alloc((size_t)N*512*4);
  float* bufC =(float*)alloc((size_t)N*512*4);
  float* e0b  =(float*)alloc((size_t)N*4);
  float* residb=(float*)alloc((size_t)N*32*4);
  char*  dyn  = ws+o;
  size_t remain = ws_size>o ? ws_size-o : 0;

  dim3 tb(256);
  dim3 nblk((unsigned)((N*32+255)/256));
  dim3 eblk((unsigned)((E+255)/256));
  dim3 qblk((unsigned)((N*64+255)/256));

  // CSR build (receiver-sorted edge order)
  hipMemsetAsync(deg,0,(size_t)N*4,stream);
  k_count<<<eblk,tb,0,stream>>>(rcv,deg,E);
  k_scan<<<dim3(1),dim3(1024),0,stream>>>(deg,rowp,cur,N);
  k_fill<<<eblk,tb,0,stream>>>(rcv,cur,eid,E);

  k_edge_setup<<<eblk,tb,0,stream>>>(vec,snd,eid,Yb,radb,snd_s,E);
  k_node_init<<<nblk,tb,0,stream>>>(embed,zarr,feats,N);

  // cast+transpose radial-MLP final weights to bf16 (per launch)
  k_cast_w2t<<<dim3((1088*64+255)/256),tb,0,stream>>>(r0w2,w2t0);
  k_cast_w2t<<<dim3((1088*64+255)/256),tb,0,stream>>>(r1w2,w2t1);

  auto run_edges=[&](bool l0, const float* hlin, const unsigned short* w2t, float* agg){
    // per-edge workspace: msgs only (rw lives in LDS inside the fused kernel)
    long rows = (long)(remain/1024);
    rows -= rows%64;
    if (rows>(long)Epad) rows=Epad;
    if (rows<64) rows=64;
    unsigned short* msgsb = (unsigned short*)dyn;
    for(long eb=0;eb<E;eb+=rows){
      long cnt = E-eb; if(cnt>rows) cnt=rows;
      dim3 g2((unsigned)((cnt+15)/16));
      if(l0) k_tp_fused<true ><<<g2,tb,0,stream>>>(hlin,Yb,hidb+(size_t)eb*64,w2t,snd_s,msgsb,(int)eb,(int)cnt);
      else   k_tp_fused<false><<<g2,tb,0,stream>>>(hlin,Yb,hidb+(size_t)eb*64,w2t,snd_s,msgsb,(int)eb,(int)cnt);
      k_seg_sum<<<qblk,tb,0,stream>>>(msgsb,rowp,agg,(int)eb,(int)cnt,N);
    }
  };

  // ---- layer 0 ----
  k_lin<<<nblk,tb,0,stream>>>(feats,bufA,up0,(const int*)nullptr,0,N);
  k_radial<<<eblk,tb,0,stream>>>(radb,r0w0,r0w1,hidb,E);
  hipMemsetAsync(bufB,0,(size_t)N*512*4,stream);
  run_edges(true,bufA,w2t0,bufB);
  k_lin<<<nblk,tb,0,stream>>>(bufB,bufC,post0,(const int*)nullptr,0,N);
  k_lin<<<nblk,tb,0,stream>>>(bufC,bufA,sel0,zarr,4096,N);
  k_tp_node<<<nblk,tb,0,stream>>>(bufA,bufB,pb0,zarr,N);
  k_lin<<<nblk,tb,0,stream>>>(bufB,feats,pblin0,(const int*)nullptr,0,N);
  k_e0<<<dim3((N+255)/256),tb,0,stream>>>(feats,ro0,e0b,N);
  k_resid<<<nblk,tb,0,stream>>>(feats,res1,zarr,residb,N);

  // ---- layer 1 ----
  k_lin<<<nblk,tb,0,stream>>>(feats,bufA,up1,(const int*)nullptr,0,N);
  k_radial<<<eblk,tb,0,stream>>>(radb,r1w0,r1w1,hidb,E);
  hipMemsetAsync(bufC,0,(size_t)N*512*4,stream);
  run_edges(false,bufA,w2t1,bufC);
  k_lin<<<nblk,tb,0,stream>>>(bufC,bufB,post1,(const int*)nullptr,0,N);
  k_tp_node<<<nblk,tb,0,stream>>>(bufB,bufA,pb1,zarr,N);
  k_lin<<<nblk,tb,0,stream>>>(bufA,bufC,pblin1,(const int*)nullptr,0,N);

  hipMemsetAsync(d_out,0,4,stream);
  k_final<<<dim3((N+255)/256),tb,0,stream>>>(bufC,residb,e0b,ro1a,ro1b,(float*)d_out,N);
}